// Round 4
// baseline (420.256 us; speedup 1.0000x reference)
//
#include <hip/hip_runtime.h>
#include <math.h>
#include <stdint.h>

#define BATCH   4
#define SEQ     2048
#define DMODEL  512
#define NHEADS  8
#define HDIM    64
#define QKV_N   (3*DMODEL)   // 1536

typedef short bf8  __attribute__((ext_vector_type(8)));   // 8 bf16 (4 VGPRs)
typedef float f32x4 __attribute__((ext_vector_type(4)));  // 4 fp32 acc

#define MFMA16(a,b,c) __builtin_amdgcn_mfma_f32_16x16x32_bf16((a),(b),(c),0,0,0)

__device__ inline unsigned short f2bf(float f){      // RNE fp32->bf16
  unsigned int u = __float_as_uint(f);
  u += 0x7FFFu + ((u >> 16) & 1u);
  return (unsigned short)(u >> 16);
}

// ---------------------------------------------------------------------------
// Fused prepass: cast x -> bf16 (blocks 0..2047), transpose+cast W_qkv
// (blocks 2048..2239), transpose+cast W_out (blocks 2240..2303).
// ---------------------------------------------------------------------------
__global__ __launch_bounds__(256) void prep(
    const float* __restrict__ x, const float* __restrict__ Wqkv,
    const float* __restrict__ Wout, unsigned short* __restrict__ Xh,
    unsigned short* __restrict__ WqkvT, unsigned short* __restrict__ WoutT)
{
  __shared__ unsigned short Ts[64][72];
  const int t = threadIdx.x;
  const int bx = blockIdx.x;
  if (bx < 2048) {
    const int i = bx*256 + t;
    const float4 a = reinterpret_cast<const float4*>(x)[2*i];
    const float4 b = reinterpret_cast<const float4*>(x)[2*i+1];
    uint4 o; unsigned short* us = reinterpret_cast<unsigned short*>(&o);
    us[0]=f2bf(a.x); us[1]=f2bf(a.y); us[2]=f2bf(a.z); us[3]=f2bf(a.w);
    us[4]=f2bf(b.x); us[5]=f2bf(b.y); us[6]=f2bf(b.z); us[7]=f2bf(b.w);
    reinterpret_cast<uint4*>(Xh)[i] = o;
    return;
  }
  const float* in; unsigned short* out; int R, C, gx, gy;
  if (bx < 2048 + 192) {
    const int bid = bx - 2048;
    gx = bid % 24; gy = bid / 24; in = Wqkv; out = WqkvT; R = DMODEL; C = QKV_N;
  } else {
    const int bid = bx - 2240;
    gx = bid % 8;  gy = bid / 8;  in = Wout; out = WoutT; R = DMODEL; C = DMODEL;
  }
  const int r0 = gy<<6, c0 = gx<<6;
  const int rr = t>>2, cs = (t&3)<<4;
#pragma unroll
  for (int p=0;p<4;++p){
    float4 v = *reinterpret_cast<const float4*>(in + (size_t)(r0+rr)*C + c0 + cs + p*4);
    Ts[rr][cs+p*4+0]=f2bf(v.x); Ts[rr][cs+p*4+1]=f2bf(v.y);
    Ts[rr][cs+p*4+2]=f2bf(v.z); Ts[rr][cs+p*4+3]=f2bf(v.w);
  }
  __syncthreads();
  const int cc = t>>2, rs = (t&3)<<4;
#pragma unroll
  for (int p=0;p<4;++p){
    ushort4 o;
    o.x = Ts[rs+p*4+0][cc]; o.y = Ts[rs+p*4+1][cc];
    o.z = Ts[rs+p*4+2][cc]; o.w = Ts[rs+p*4+3][cc];
    *reinterpret_cast<ushort4*>(out + (size_t)(c0+cc)*R + r0 + rs + p*4) = o;
  }
}

// ---------------------------------------------------------------------------
// MFMA GEMM A: qkv = Xh @ WqkvT^T, scatter epilogue into bf16 Q,K,V
// [B*H][S][64] (reference's flat-reinterpret scramble). Q pre-scaled 0.125.
// ---------------------------------------------------------------------------
__global__ __launch_bounds__(256) void gemm_qkv_mfma(
    const unsigned short* __restrict__ A, const unsigned short* __restrict__ Bt,
    unsigned short* __restrict__ Qb, unsigned short* __restrict__ Kb,
    unsigned short* __restrict__ Vb)
{
  __shared__ unsigned short As[128][72];
  __shared__ unsigned short Bs[128][72];
  const int t = threadIdx.x;
  const int w = t>>6, lane = t&63, quad = lane>>4, l15 = lane&15;
  const int wr = (w>>1)<<6, wc = (w&1)<<6;
  const int m0 = blockIdx.y<<7, n0 = blockIdx.x<<7;
  const int row = t>>3, seg = t&7;
  const unsigned short* Agp = A  + (size_t)(m0+row)*DMODEL + seg*8;
  const unsigned short* Bgp = Bt + (size_t)(n0+row)*DMODEL + seg*8;
  uint4 ga[4], gb[4];
#pragma unroll
  for (int p=0;p<4;++p){
    ga[p] = *reinterpret_cast<const uint4*>(Agp + (size_t)p*32*DMODEL);
    gb[p] = *reinterpret_cast<const uint4*>(Bgp + (size_t)p*32*DMODEL);
  }
  f32x4 acc[4][4];
#pragma unroll
  for (int i=0;i<4;++i)
#pragma unroll
    for (int j=0;j<4;++j) acc[i][j] = (f32x4){0.f,0.f,0.f,0.f};

  for (int k0=0;k0<DMODEL;k0+=64){
    __syncthreads();
#pragma unroll
    for (int p=0;p<4;++p){
      *reinterpret_cast<uint4*>(&As[row+p*32][seg*8]) = ga[p];
      *reinterpret_cast<uint4*>(&Bs[row+p*32][seg*8]) = gb[p];
    }
    __syncthreads();
    if (k0+64 < DMODEL){
#pragma unroll
      for (int p=0;p<4;++p){
        ga[p] = *reinterpret_cast<const uint4*>(Agp + (size_t)p*32*DMODEL + k0+64);
        gb[p] = *reinterpret_cast<const uint4*>(Bgp + (size_t)p*32*DMODEL + k0+64);
      }
    }
#pragma unroll
    for (int ks=0;ks<2;++ks){
      bf8 af[4], bfr[4];
#pragma unroll
      for (int mi=0;mi<4;++mi)
        af[mi]  = *reinterpret_cast<const bf8*>(&As[wr+mi*16+l15][ks*32+quad*8]);
#pragma unroll
      for (int nj=0;nj<4;++nj)
        bfr[nj] = *reinterpret_cast<const bf8*>(&Bs[wc+nj*16+l15][ks*32+quad*8]);
#pragma unroll
      for (int mi=0;mi<4;++mi)
#pragma unroll
        for (int nj=0;nj<4;++nj) acc[mi][nj] = MFMA16(af[mi], bfr[nj], acc[mi][nj]);
    }
  }
#pragma unroll
  for (int mi=0;mi<4;++mi){
#pragma unroll
    for (int i=0;i<4;++i){
      const int m = m0 + wr + mi*16 + quad*4 + i;
      const int bb = m>>11, s = m&2047;
#pragma unroll
      for (int nj=0;nj<4;++nj){
        const int c = n0 + wc + nj*16 + l15;
        const int h = c/192, e = c - h*192;
        const int n = (s<<3)+h;
        const int hp = n>>11, sp = n&2047;
        const size_t idx = ((size_t)((bb<<3)+hp)*SEQ + sp)*HDIM + (e&63);
        float v = acc[mi][nj][i];
        if (e < 64) v *= 0.125f;              // fold 1/sqrt(hd) into Q (exact)
        unsigned short* dst = (e<64)?Qb:((e<128)?Kb:Vb);
        dst[idx] = f2bf(v);
      }
    }
  }
}

// ---------------------------------------------------------------------------
// V [bh][s][d] -> VT [bh][d][s]  (one-shot transpose; PV B-frags then load
// contiguous from global)
// ---------------------------------------------------------------------------
__global__ __launch_bounds__(256) void v_transpose(
    const unsigned short* __restrict__ V, unsigned short* __restrict__ VT)
{
  __shared__ unsigned short Td[64][76];      // [d][s], stride 152 B (8B-aligned)
  const int t = threadIdx.x;
  const int bh = blockIdx.y, s0 = blockIdx.x<<6;
  const unsigned short* Vp = V + ((size_t)bh*SEQ + s0)*HDIM;
  const int sr = t>>2, db = (t&3)<<4;
  uint4 a = *reinterpret_cast<const uint4*>(Vp + (size_t)sr*HDIM + db);
  uint4 c = *reinterpret_cast<const uint4*>(Vp + (size_t)sr*HDIM + db + 8);
  const unsigned short* ua = reinterpret_cast<const unsigned short*>(&a);
  const unsigned short* uc = reinterpret_cast<const unsigned short*>(&c);
#pragma unroll
  for (int j=0;j<8;++j) Td[db+j][sr]   = ua[j];
#pragma unroll
  for (int j=0;j<8;++j) Td[db+8+j][sr] = uc[j];
  __syncthreads();
  const int L = t&15, d0 = t>>4;
  unsigned short* Op = VT + (size_t)bh*HDIM*SEQ + s0 + (L<<2);
#pragma unroll
  for (int cc=0;cc<4;++cc){
    const int d = d0 + (cc<<4);
    *reinterpret_cast<unsigned long long*>(Op + (size_t)d*SEQ) =
        *reinterpret_cast<const unsigned long long*>(&Td[d][L<<2]);
  }
}

// ---------------------------------------------------------------------------
// MFMA flash attention, no-max softmax, barrier-free K-loop.
// S col (nf,l15) = key 4*l15+nf  ->  P rows store as one ds_write_b64/lane,
// A-frag reads natural key order, V^T B-frags from global.
// ---------------------------------------------------------------------------
__global__ __launch_bounds__(256, 4) void attn_mfma(
    const unsigned short* __restrict__ Q, const unsigned short* __restrict__ K,
    const unsigned short* __restrict__ VT, const int* __restrict__ mask,
    unsigned short* __restrict__ O)
{
  __shared__ unsigned long long mbits[32];   // 2048-bit key/query validity
  __shared__ unsigned short Pl[4][16][72];   // wave-private P strip [q][key]
  const int t = threadIdx.x;
  const int w = t>>6, lane = t&63, quad = lane>>4, l15 = lane&15;
  const int bh = blockIdx.y, b = bh>>3;
  const int q0 = blockIdx.x<<6, qs = q0 + (w<<4);
  const int* mb = mask + b*SEQ;
  const f32x4 Z4 = {0.f, 0.f, 0.f, 0.f};
#pragma unroll
  for (int i=0;i<8;++i){
    const unsigned long long bal = __ballot(mb[i*256 + t] != 0);
    if (lane == 0) mbits[i*4 + w] = bal;
  }
  __syncthreads();

  const unsigned short* Qp = Q + ((size_t)bh*SEQ + qs + l15)*HDIM + (quad<<3);
  const bf8 qf0 = *reinterpret_cast<const bf8*>(Qp);
  const bf8 qf1 = *reinterpret_cast<const bf8*>(Qp + 32);
  const unsigned short* Kb = K  + (size_t)bh*SEQ*HDIM;
  const unsigned short* Vb = VT + (size_t)bh*HDIM*SEQ;

  f32x4 of[4]; float lsum[4];
#pragma unroll
  for (int i=0;i<4;++i){ of[i]=Z4; lsum[i]=0.f; }

  for (int kt=0; kt<SEQ; kt+=64){
    const unsigned int msel =
        (unsigned int)(mbits[kt>>6] >> (l15<<2)) & 0xFu;  // 4 key bits, this lane
    f32x4 sc[4];
#pragma unroll
    for (int nf=0;nf<4;++nf){
      const unsigned short* kp = Kb + (size_t)(kt + (l15<<2) + nf)*HDIM + (quad<<3);
      const bf8 k0 = *reinterpret_cast<const bf8*>(kp);
      const bf8 k1 = *reinterpret_cast<const bf8*>(kp + 32);
      f32x4 s = MFMA16(qf0, k0, Z4);
      sc[nf] = MFMA16(qf1, k1, s);
    }
    float pv[4][4];
#pragma unroll
    for (int nf=0;nf<4;++nf){
      const bool on = (msel >> nf) & 1u;
#pragma unroll
      for (int i=0;i<4;++i)
        pv[nf][i] = on ? __expf(sc[nf][i]) : 0.f;   // scores pre-scaled via Q
    }
#pragma unroll
    for (int i=0;i<4;++i)
      lsum[i] += (pv[0][i]+pv[1][i]) + (pv[2][i]+pv[3][i]);
#pragma unroll
    for (int i=0;i<4;++i){
      const unsigned int lo = (unsigned int)f2bf(pv[0][i]) | ((unsigned int)f2bf(pv[1][i])<<16);
      const unsigned int hi = (unsigned int)f2bf(pv[2][i]) | ((unsigned int)f2bf(pv[3][i])<<16);
      *reinterpret_cast<unsigned long long*>(&Pl[w][(quad<<2)+i][l15<<2]) =
          ((unsigned long long)hi<<32) | lo;
    }
    const bf8 pa0 = *reinterpret_cast<const bf8*>(&Pl[w][l15][quad<<3]);
    const bf8 pa1 = *reinterpret_cast<const bf8*>(&Pl[w][l15][32+(quad<<3)]);
#pragma unroll
    for (int nf=0;nf<4;++nf){
      const unsigned short* vp = Vb + (size_t)((nf<<4)+l15)*SEQ + kt + (quad<<3);
      const bf8 v0 = *reinterpret_cast<const bf8*>(vp);
      const bf8 v1 = *reinterpret_cast<const bf8*>(vp + 32);
      f32x4 o = MFMA16(pa0, v0, of[nf]);
      of[nf] = MFMA16(pa1, v1, o);
    }
  }

#pragma unroll
  for (int i=0;i<4;++i){
    float s = lsum[i];
    s += __shfl_xor(s,1); s += __shfl_xor(s,2);
    s += __shfl_xor(s,4); s += __shfl_xor(s,8);
    lsum[i] = s;
  }
  const unsigned long long qw = mbits[q0>>6];
  unsigned short* Op = O + (size_t)bh*SEQ*HDIM;
#pragma unroll
  for (int i=0;i<4;++i){
    const int q = qs + (quad<<2) + i;
    const bool qv = (qw >> (q & 63)) & 1ull;
    const float inv = (qv && lsum[i] > 0.f) ? 1.f/lsum[i] : 0.f;
#pragma unroll
    for (int nf=0;nf<4;++nf)
      Op[(size_t)q*HDIM + (nf<<4) + l15] = f2bf(of[nf][i]*inv);
  }
}

// ---------------------------------------------------------------------------
// MFMA GEMM C: out = Ob @ WoutT^T, fp32 output.
// ---------------------------------------------------------------------------
__global__ __launch_bounds__(256) void gemm_out_mfma(
    const unsigned short* __restrict__ A, const unsigned short* __restrict__ Bt,
    float* __restrict__ Out)
{
  __shared__ unsigned short As[128][72];
  __shared__ unsigned short Bs[128][72];
  const int t = threadIdx.x;
  const int w = t>>6, lane = t&63, quad = lane>>4, l15 = lane&15;
  const int wr = (w>>1)<<6, wc = (w&1)<<6;
  const int m0 = blockIdx.y<<7, n0 = blockIdx.x<<7;
  const int row = t>>3, seg = t&7;
  const unsigned short* Agp = A  + (size_t)(m0+row)*DMODEL + seg*8;
  const unsigned short* Bgp = Bt + (size_t)(n0+row)*DMODEL + seg*8;
  uint4 ga[4], gb[4];
#pragma unroll
  for (int p=0;p<4;++p){
    ga[p] = *reinterpret_cast<const uint4*>(Agp + (size_t)p*32*DMODEL);
    gb[p] = *reinterpret_cast<const uint4*>(Bgp + (size_t)p*32*DMODEL);
  }
  f32x4 acc[4][4];
#pragma unroll
  for (int i=0;i<4;++i)
#pragma unroll
    for (int j=0;j<4;++j) acc[i][j] = (f32x4){0.f,0.f,0.f,0.f};

  for (int k0=0;k0<DMODEL;k0+=64){
    __syncthreads();
#pragma unroll
    for (int p=0;p<4;++p){
      *reinterpret_cast<uint4*>(&As[row+p*32][seg*8]) = ga[p];
      *reinterpret_cast<uint4*>(&Bs[row+p*32][seg*8]) = gb[p];
    }
    __syncthreads();
    if (k0+64 < DMODEL){
#pragma unroll
      for (int p=0;p<4;++p){
        ga[p] = *reinterpret_cast<const uint4*>(Agp + (size_t)p*32*DMODEL + k0+64);
        gb[p] = *reinterpret_cast<const uint4*>(Bgp + (size_t)p*32*DMODEL + k0+64);
      }
    }
#pragma unroll
    for (int ks=0;ks<2;++ks){
      bf8 af[4], bfr[4];
#pragma unroll
      for (int mi=0;mi<4;++mi)
        af[mi]  = *reinterpret_cast<const bf8*>(&As[wr+mi*16+l15][ks*32+quad*8]);
#pragma unroll
      for (int nj=0;nj<4;++nj)
        bfr[nj] = *reinterpret_cast<const bf8*>(&Bs[wc+nj*16+l15][ks*32+quad*8]);
#pragma unroll
      for (int mi=0;mi<4;++mi)
#pragma unroll
        for (int nj=0;nj<4;++nj) acc[mi][nj] = MFMA16(af[mi], bfr[nj], acc[mi][nj]);
    }
  }
#pragma unroll
  for (int mi=0;mi<4;++mi)
#pragma unroll
    for (int i=0;i<4;++i){
      const int m = m0 + wr + mi*16 + quad*4 + i;
#pragma unroll
      for (int nj=0;nj<4;++nj)
        Out[(size_t)m*DMODEL + n0 + wc + nj*16 + l15] = acc[mi][nj][i];
    }
}

// ---------------------------------------------------------------------------
extern "C" void kernel_launch(void* const* d_in, const int* in_sizes, int n_in,
                              void* d_out, int out_size, void* d_ws, size_t ws_size,
                              hipStream_t stream) {
  (void)in_sizes; (void)n_in; (void)out_size; (void)ws_size;
  const float* x     = (const float*)d_in[0];
  const int*   pmask = (const int*)d_in[2];
  const float* Wqkv  = (const float*)d_in[3];
  const float* Wout  = (const float*)d_in[4];
  float* out = (float*)d_out;

  const size_t per = (size_t)BATCH*NHEADS*SEQ*HDIM;     // 4,194,304
  unsigned short* Xh    = (unsigned short*)d_ws;        // 8192*512
  unsigned short* WqkvT = Xh    + (size_t)8192*512;
  unsigned short* WoutT = WqkvT + (size_t)1536*512;
  unsigned short* Qb    = WoutT + (size_t)512*512;
  unsigned short* Kb    = Qb  + per;
  unsigned short* Vb    = Kb  + per;
  unsigned short* VbT   = Vb  + per;
  unsigned short* Ob    = VbT + per;                    // ~52 MB total

  prep<<<2304, 256, 0, stream>>>(x, Wqkv, Wout, Xh, WqkvT, WoutT);
  gemm_qkv_mfma<<<dim3(QKV_N/128, 8192/128), 256, 0, stream>>>(Xh, WqkvT, Qb, Kb, Vb);
  v_transpose<<<dim3(SEQ/64, BATCH*NHEADS), 256, 0, stream>>>(Vb, VbT);
  attn_mfma<<<dim3(SEQ/64, BATCH*NHEADS), 256, 0, stream>>>(Qb, Kb, VbT, pmask, Ob);
  gemm_out_mfma<<<dim3(DMODEL/128, 8192/128), 256, 0, stream>>>(Ob, WoutT, out);
}

// Round 5
// 261.735 us; speedup vs baseline: 1.6057x; 1.6057x over previous
//
#include <hip/hip_runtime.h>
#include <math.h>
#include <stdint.h>

#define BATCH   4
#define SEQ     2048
#define DMODEL  512
#define NHEADS  8
#define HDIM    64
#define QKV_N   (3*DMODEL)   // 1536

typedef short bf8  __attribute__((ext_vector_type(8)));   // 8 bf16 (4 VGPRs)
typedef float f32x4 __attribute__((ext_vector_type(4)));  // 4 fp32 acc

#define MFMA16(a,b,c) __builtin_amdgcn_mfma_f32_16x16x32_bf16((a),(b),(c),0,0,0)

__device__ inline unsigned short f2bf(float f){      // RNE fp32->bf16
  unsigned int u = __float_as_uint(f);
  u += 0x7FFFu + ((u >> 16) & 1u);
  return (unsigned short)(u >> 16);
}

// ---------------------------------------------------------------------------
// Fused prepass: cast x -> bf16 (blocks 0..2047), transpose+cast W_qkv
// (blocks 2048..2239), transpose+cast W_out (blocks 2240..2303).
// ---------------------------------------------------------------------------
__global__ __launch_bounds__(256) void prep(
    const float* __restrict__ x, const float* __restrict__ Wqkv,
    const float* __restrict__ Wout, unsigned short* __restrict__ Xh,
    unsigned short* __restrict__ WqkvT, unsigned short* __restrict__ WoutT)
{
  __shared__ unsigned short Ts[64][72];
  const int t = threadIdx.x;
  const int bx = blockIdx.x;
  if (bx < 2048) {
    const int i = bx*256 + t;
    const float4 a = reinterpret_cast<const float4*>(x)[2*i];
    const float4 b = reinterpret_cast<const float4*>(x)[2*i+1];
    uint4 o; unsigned short* us = reinterpret_cast<unsigned short*>(&o);
    us[0]=f2bf(a.x); us[1]=f2bf(a.y); us[2]=f2bf(a.z); us[3]=f2bf(a.w);
    us[4]=f2bf(b.x); us[5]=f2bf(b.y); us[6]=f2bf(b.z); us[7]=f2bf(b.w);
    reinterpret_cast<uint4*>(Xh)[i] = o;
    return;
  }
  const float* in; unsigned short* out; int R, C, gx, gy;
  if (bx < 2048 + 192) {
    const int bid = bx - 2048;
    gx = bid % 24; gy = bid / 24; in = Wqkv; out = WqkvT; R = DMODEL; C = QKV_N;
  } else {
    const int bid = bx - 2240;
    gx = bid % 8;  gy = bid / 8;  in = Wout; out = WoutT; R = DMODEL; C = DMODEL;
  }
  const int r0 = gy<<6, c0 = gx<<6;
  const int rr = t>>2, cs = (t&3)<<4;
#pragma unroll
  for (int p=0;p<4;++p){
    float4 v = *reinterpret_cast<const float4*>(in + (size_t)(r0+rr)*C + c0 + cs + p*4);
    Ts[rr][cs+p*4+0]=f2bf(v.x); Ts[rr][cs+p*4+1]=f2bf(v.y);
    Ts[rr][cs+p*4+2]=f2bf(v.z); Ts[rr][cs+p*4+3]=f2bf(v.w);
  }
  __syncthreads();
  const int cc = t>>2, rs = (t&3)<<4;
#pragma unroll
  for (int p=0;p<4;++p){
    ushort4 o;
    o.x = Ts[rs+p*4+0][cc]; o.y = Ts[rs+p*4+1][cc];
    o.z = Ts[rs+p*4+2][cc]; o.w = Ts[rs+p*4+3][cc];
    *reinterpret_cast<ushort4*>(out + (size_t)(c0+cc)*R + r0 + rs + p*4) = o;
  }
}

// ---------------------------------------------------------------------------
// MFMA GEMM A: qkv = Xh @ WqkvT^T, scatter epilogue into bf16 Q,K,V
// [B*H][S][64] (reference's flat-reinterpret scramble). Q pre-scaled 0.125.
// ---------------------------------------------------------------------------
__global__ __launch_bounds__(256) void gemm_qkv_mfma(
    const unsigned short* __restrict__ A, const unsigned short* __restrict__ Bt,
    unsigned short* __restrict__ Qb, unsigned short* __restrict__ Kb,
    unsigned short* __restrict__ Vb)
{
  __shared__ unsigned short As[128][72];
  __shared__ unsigned short Bs[128][72];
  const int t = threadIdx.x;
  const int w = t>>6, lane = t&63, quad = lane>>4, l15 = lane&15;
  const int wr = (w>>1)<<6, wc = (w&1)<<6;
  const int m0 = blockIdx.y<<7, n0 = blockIdx.x<<7;
  const int row = t>>3, seg = t&7;
  const unsigned short* Agp = A  + (size_t)(m0+row)*DMODEL + seg*8;
  const unsigned short* Bgp = Bt + (size_t)(n0+row)*DMODEL + seg*8;
  uint4 ga[4], gb[4];
#pragma unroll
  for (int p=0;p<4;++p){
    ga[p] = *reinterpret_cast<const uint4*>(Agp + (size_t)p*32*DMODEL);
    gb[p] = *reinterpret_cast<const uint4*>(Bgp + (size_t)p*32*DMODEL);
  }
  f32x4 acc[4][4];
#pragma unroll
  for (int i=0;i<4;++i)
#pragma unroll
    for (int j=0;j<4;++j) acc[i][j] = (f32x4){0.f,0.f,0.f,0.f};

  for (int k0=0;k0<DMODEL;k0+=64){
    __syncthreads();
#pragma unroll
    for (int p=0;p<4;++p){
      *reinterpret_cast<uint4*>(&As[row+p*32][seg*8]) = ga[p];
      *reinterpret_cast<uint4*>(&Bs[row+p*32][seg*8]) = gb[p];
    }
    __syncthreads();
    if (k0+64 < DMODEL){
#pragma unroll
      for (int p=0;p<4;++p){
        ga[p] = *reinterpret_cast<const uint4*>(Agp + (size_t)p*32*DMODEL + k0+64);
        gb[p] = *reinterpret_cast<const uint4*>(Bgp + (size_t)p*32*DMODEL + k0+64);
      }
    }
#pragma unroll
    for (int ks=0;ks<2;++ks){
      bf8 af[4], bfr[4];
#pragma unroll
      for (int mi=0;mi<4;++mi)
        af[mi]  = *reinterpret_cast<const bf8*>(&As[wr+mi*16+l15][ks*32+quad*8]);
#pragma unroll
      for (int nj=0;nj<4;++nj)
        bfr[nj] = *reinterpret_cast<const bf8*>(&Bs[wc+nj*16+l15][ks*32+quad*8]);
#pragma unroll
      for (int mi=0;mi<4;++mi)
#pragma unroll
        for (int nj=0;nj<4;++nj) acc[mi][nj] = MFMA16(af[mi], bfr[nj], acc[mi][nj]);
    }
  }
#pragma unroll
  for (int mi=0;mi<4;++mi){
#pragma unroll
    for (int i=0;i<4;++i){
      const int m = m0 + wr + mi*16 + quad*4 + i;
      const int bb = m>>11, s = m&2047;
#pragma unroll
      for (int nj=0;nj<4;++nj){
        const int c = n0 + wc + nj*16 + l15;
        const int h = c/192, e = c - h*192;
        const int n = (s<<3)+h;
        const int hp = n>>11, sp = n&2047;
        const size_t idx = ((size_t)((bb<<3)+hp)*SEQ + sp)*HDIM + (e&63);
        float v = acc[mi][nj][i];
        if (e < 64) v *= 0.125f;              // fold 1/sqrt(hd) into Q (exact)
        unsigned short* dst = (e<64)?Qb:((e<128)?Kb:Vb);
        dst[idx] = f2bf(v);
      }
    }
  }
}

// ---------------------------------------------------------------------------
// V [bh][s][d] -> VT [bh][d][s]  (one-shot transpose)
// ---------------------------------------------------------------------------
__global__ __launch_bounds__(256) void v_transpose(
    const unsigned short* __restrict__ V, unsigned short* __restrict__ VT)
{
  __shared__ unsigned short Td[64][76];
  const int t = threadIdx.x;
  const int bh = blockIdx.y, s0 = blockIdx.x<<6;
  const unsigned short* Vp = V + ((size_t)bh*SEQ + s0)*HDIM;
  const int sr = t>>2, db = (t&3)<<4;
  uint4 a = *reinterpret_cast<const uint4*>(Vp + (size_t)sr*HDIM + db);
  uint4 c = *reinterpret_cast<const uint4*>(Vp + (size_t)sr*HDIM + db + 8);
  const unsigned short* ua = reinterpret_cast<const unsigned short*>(&a);
  const unsigned short* uc = reinterpret_cast<const unsigned short*>(&c);
#pragma unroll
  for (int j=0;j<8;++j) Td[db+j][sr]   = ua[j];
#pragma unroll
  for (int j=0;j<8;++j) Td[db+8+j][sr] = uc[j];
  __syncthreads();
  const int L = t&15, d0 = t>>4;
  unsigned short* Op = VT + (size_t)bh*HDIM*SEQ + s0 + (L<<2);
#pragma unroll
  for (int cc=0;cc<4;++cc){
    const int d = d0 + (cc<<4);
    *reinterpret_cast<unsigned long long*>(Op + (size_t)d*SEQ) =
        *reinterpret_cast<const unsigned long long*>(&Td[d][L<<2]);
  }
}

// ---------------------------------------------------------------------------
// MFMA flash attention v3: LDS-staged K & V^T tiles (coalesced, shared by all
// 4 waves), 32 queries/wave (2 strips), no-max softmax, natural-key P layout
// via rho-permuted K staging: key k stored at LDS row (k&3)*16+(k>>2) so
// B-frag row nf*16+l15 = key 4*l15+nf (round-4-verified S mapping).
// ---------------------------------------------------------------------------
__global__ __launch_bounds__(256, 2) void attn_mfma(
    const unsigned short* __restrict__ Q, const unsigned short* __restrict__ K,
    const unsigned short* __restrict__ VT, const int* __restrict__ mask,
    unsigned short* __restrict__ O)
{
  __shared__ unsigned long long mbits[32];   // 2048-bit validity
  __shared__ unsigned short Ks[64][72];      // rho-permuted K tile [row][d]
  __shared__ unsigned short Vs[64][72];      // V^T tile [d][key]
  __shared__ unsigned short Pl[4][32][72];   // wave-private P [q][key]
  const int t = threadIdx.x;
  const int w = t>>6, lane = t&63, quad = lane>>4, l15 = lane&15;
  const int bh = blockIdx.y, b = bh>>3;
  const int q0 = blockIdx.x<<7;              // 128 queries per block
  const int qs = q0 + (w<<5);                // 32 per wave
  const int* mb = mask + b*SEQ;
  const f32x4 Z4 = {0.f,0.f,0.f,0.f};
#pragma unroll
  for (int i=0;i<8;++i){
    const unsigned long long bal = __ballot(mb[i*256 + t] != 0);
    if (lane == 0) mbits[i*4 + w] = bal;
  }

  const unsigned short* Qbase = Q + (size_t)bh*SEQ*HDIM;
  bf8 qf[2][2];
#pragma unroll
  for (int a=0;a<2;++a){
    const unsigned short* qp = Qbase + (size_t)(qs + a*16 + l15)*HDIM + (quad<<3);
    qf[a][0] = *reinterpret_cast<const bf8*>(qp);
    qf[a][1] = *reinterpret_cast<const bf8*>(qp + 32);
  }
  const unsigned short* Kb = K  + (size_t)bh*SEQ*HDIM;
  const unsigned short* Vg = VT + (size_t)bh*HDIM*SEQ;

  const int srow = t>>2, sc4 = (t&3)<<4;             // staging: row, 16-elem col
  const int krow = ((srow&3)<<4) + (srow>>2);        // rho(srow)

  f32x4 of[2][4]; float lsum[2][4];
#pragma unroll
  for (int a=0;a<2;++a)
#pragma unroll
    for (int i=0;i<4;++i){ of[a][i]=Z4; lsum[a][i]=0.f; }

  __syncthreads();                                   // mbits visible

  for (int kt=0; kt<SEQ; kt+=64){
    // coalesced global loads for staging (issued before barrier for overlap)
    const unsigned short* kp = Kb + (size_t)(kt+srow)*HDIM + sc4;
    const uint4 gk0 = *reinterpret_cast<const uint4*>(kp);
    const uint4 gk1 = *reinterpret_cast<const uint4*>(kp + 8);
    const unsigned short* vp = Vg + (size_t)srow*SEQ + kt + sc4;
    const uint4 gv0 = *reinterpret_cast<const uint4*>(vp);
    const uint4 gv1 = *reinterpret_cast<const uint4*>(vp + 8);
    __syncthreads();                                 // prev-tile readers done
    *reinterpret_cast<uint4*>(&Ks[krow][sc4])     = gk0;
    *reinterpret_cast<uint4*>(&Ks[krow][sc4+8])   = gk1;
    *reinterpret_cast<uint4*>(&Vs[srow][sc4])     = gv0;
    *reinterpret_cast<uint4*>(&Vs[srow][sc4+8])   = gv1;
    __syncthreads();                                 // tiles visible

    const unsigned int msel =
        (unsigned int)(mbits[kt>>6] >> (l15<<2)) & 0xFu;

    // K fragments (shared by both strips)
    bf8 kf[4][2];
#pragma unroll
    for (int nf=0;nf<4;++nf){
      kf[nf][0] = *reinterpret_cast<const bf8*>(&Ks[nf*16+l15][quad<<3]);
      kf[nf][1] = *reinterpret_cast<const bf8*>(&Ks[nf*16+l15][32+(quad<<3)]);
    }

#pragma unroll
    for (int a=0;a<2;++a){
      f32x4 sc[4];
#pragma unroll
      for (int nf=0;nf<4;++nf){
        f32x4 s = MFMA16(qf[a][0], kf[nf][0], Z4);
        sc[nf] = MFMA16(qf[a][1], kf[nf][1], s);
      }
      float pv[4][4];
#pragma unroll
      for (int nf=0;nf<4;++nf){
        const bool on = (msel >> nf) & 1u;
#pragma unroll
        for (int i=0;i<4;++i)
          pv[nf][i] = on ? __expf(sc[nf][i]) : 0.f;  // Q pre-scaled by 0.125
      }
#pragma unroll
      for (int i=0;i<4;++i)
        lsum[a][i] += (pv[0][i]+pv[1][i]) + (pv[2][i]+pv[3][i]);
#pragma unroll
      for (int i=0;i<4;++i){
        const unsigned int lo = (unsigned int)f2bf(pv[0][i]) | ((unsigned int)f2bf(pv[1][i])<<16);
        const unsigned int hi = (unsigned int)f2bf(pv[2][i]) | ((unsigned int)f2bf(pv[3][i])<<16);
        *reinterpret_cast<unsigned long long*>(&Pl[w][a*16+(quad<<2)+i][l15<<2]) =
            ((unsigned long long)hi<<32) | lo;
      }
    }

    // PV: A = P strips, B = V^T (shared)
    bf8 pa[2][2];
#pragma unroll
    for (int a=0;a<2;++a){
      pa[a][0] = *reinterpret_cast<const bf8*>(&Pl[w][a*16+l15][quad<<3]);
      pa[a][1] = *reinterpret_cast<const bf8*>(&Pl[w][a*16+l15][32+(quad<<3)]);
    }
#pragma unroll
    for (int nf=0;nf<4;++nf){
      const bf8 v0 = *reinterpret_cast<const bf8*>(&Vs[nf*16+l15][quad<<3]);
      const bf8 v1 = *reinterpret_cast<const bf8*>(&Vs[nf*16+l15][32+(quad<<3)]);
#pragma unroll
      for (int a=0;a<2;++a){
        f32x4 o = MFMA16(pa[a][0], v0, of[a][nf]);
        of[a][nf] = MFMA16(pa[a][1], v1, o);
      }
    }
  }

  // final reduce + epilogue
#pragma unroll
  for (int a=0;a<2;++a)
#pragma unroll
    for (int i=0;i<4;++i){
      float s = lsum[a][i];
      s += __shfl_xor(s,1); s += __shfl_xor(s,2);
      s += __shfl_xor(s,4); s += __shfl_xor(s,8);
      lsum[a][i] = s;
    }
  unsigned short* Op = O + (size_t)bh*SEQ*HDIM;
#pragma unroll
  for (int a=0;a<2;++a){
    const unsigned long long qw = mbits[(qs + a*16) >> 6];
#pragma unroll
    for (int i=0;i<4;++i){
      const int q = qs + a*16 + (quad<<2) + i;
      const bool qv = (qw >> (q & 63)) & 1ull;
      const float inv = (qv && lsum[a][i] > 0.f) ? 1.f/lsum[a][i] : 0.f;
#pragma unroll
      for (int nf=0;nf<4;++nf)
        Op[(size_t)q*HDIM + (nf<<4) + l15] = f2bf(of[a][nf][i]*inv);
    }
  }
}

// ---------------------------------------------------------------------------
// MFMA GEMM C: out = Ob @ WoutT^T, fp32 output.
// ---------------------------------------------------------------------------
__global__ __launch_bounds__(256) void gemm_out_mfma(
    const unsigned short* __restrict__ A, const unsigned short* __restrict__ Bt,
    float* __restrict__ Out)
{
  __shared__ unsigned short As[128][72];
  __shared__ unsigned short Bs[128][72];
  const int t = threadIdx.x;
  const int w = t>>6, lane = t&63, quad = lane>>4, l15 = lane&15;
  const int wr = (w>>1)<<6, wc = (w&1)<<6;
  const int m0 = blockIdx.y<<7, n0 = blockIdx.x<<7;
  const int row = t>>3, seg = t&7;
  const unsigned short* Agp = A  + (size_t)(m0+row)*DMODEL + seg*8;
  const unsigned short* Bgp = Bt + (size_t)(n0+row)*DMODEL + seg*8;
  uint4 ga[4], gb[4];
#pragma unroll
  for (int p=0;p<4;++p){
    ga[p] = *reinterpret_cast<const uint4*>(Agp + (size_t)p*32*DMODEL);
    gb[p] = *reinterpret_cast<const uint4*>(Bgp + (size_t)p*32*DMODEL);
  }
  f32x4 acc[4][4];
#pragma unroll
  for (int i=0;i<4;++i)
#pragma unroll
    for (int j=0;j<4;++j) acc[i][j] = (f32x4){0.f,0.f,0.f,0.f};

  for (int k0=0;k0<DMODEL;k0+=64){
    __syncthreads();
#pragma unroll
    for (int p=0;p<4;++p){
      *reinterpret_cast<uint4*>(&As[row+p*32][seg*8]) = ga[p];
      *reinterpret_cast<uint4*>(&Bs[row+p*32][seg*8]) = gb[p];
    }
    __syncthreads();
    if (k0+64 < DMODEL){
#pragma unroll
      for (int p=0;p<4;++p){
        ga[p] = *reinterpret_cast<const uint4*>(Agp + (size_t)p*32*DMODEL + k0+64);
        gb[p] = *reinterpret_cast<const uint4*>(Bgp + (size_t)p*32*DMODEL + k0+64);
      }
    }
#pragma unroll
    for (int ks=0;ks<2;++ks){
      bf8 af[4], bfr[4];
#pragma unroll
      for (int mi=0;mi<4;++mi)
        af[mi]  = *reinterpret_cast<const bf8*>(&As[wr+mi*16+l15][ks*32+quad*8]);
#pragma unroll
      for (int nj=0;nj<4;++nj)
        bfr[nj] = *reinterpret_cast<const bf8*>(&Bs[wc+nj*16+l15][ks*32+quad*8]);
#pragma unroll
      for (int mi=0;mi<4;++mi)
#pragma unroll
        for (int nj=0;nj<4;++nj) acc[mi][nj] = MFMA16(af[mi], bfr[nj], acc[mi][nj]);
    }
  }
#pragma unroll
  for (int mi=0;mi<4;++mi)
#pragma unroll
    for (int i=0;i<4;++i){
      const int m = m0 + wr + mi*16 + quad*4 + i;
#pragma unroll
      for (int nj=0;nj<4;++nj)
        Out[(size_t)m*DMODEL + n0 + wc + nj*16 + l15] = acc[mi][nj][i];
    }
}

// ---------------------------------------------------------------------------
extern "C" void kernel_launch(void* const* d_in, const int* in_sizes, int n_in,
                              void* d_out, int out_size, void* d_ws, size_t ws_size,
                              hipStream_t stream) {
  (void)in_sizes; (void)n_in; (void)out_size; (void)ws_size;
  const float* x     = (const float*)d_in[0];
  const int*   pmask = (const int*)d_in[2];
  const float* Wqkv  = (const float*)d_in[3];
  const float* Wout  = (const float*)d_in[4];
  float* out = (float*)d_out;

  const size_t per = (size_t)BATCH*NHEADS*SEQ*HDIM;     // 4,194,304
  unsigned short* Xh    = (unsigned short*)d_ws;
  unsigned short* WqkvT = Xh    + (size_t)8192*512;
  unsigned short* WoutT = WqkvT + (size_t)1536*512;
  unsigned short* Qb    = WoutT + (size_t)512*512;
  unsigned short* Kb    = Qb  + per;
  unsigned short* Vb    = Kb  + per;
  unsigned short* VbT   = Vb  + per;
  unsigned short* Ob    = VbT + per;                    // ~52 MB total

  prep<<<2304, 256, 0, stream>>>(x, Wqkv, Wout, Xh, WqkvT, WoutT);
  gemm_qkv_mfma<<<dim3(QKV_N/128, 8192/128), 256, 0, stream>>>(Xh, WqkvT, Qb, Kb, Vb);
  v_transpose<<<dim3(SEQ/64, BATCH*NHEADS), 256, 0, stream>>>(Vb, VbT);
  attn_mfma<<<dim3(SEQ/128, BATCH*NHEADS), 256, 0, stream>>>(Qb, Kb, VbT, pmask, Ob);
  gemm_out_mfma<<<dim3(DMODEL/128, 8192/128), 256, 0, stream>>>(Ob, WoutT, out);
}

// Round 6
// 253.922 us; speedup vs baseline: 1.6551x; 1.0308x over previous
//
#include <hip/hip_runtime.h>
#include <math.h>
#include <stdint.h>

#define BATCH   4
#define SEQ     2048
#define DMODEL  512
#define NHEADS  8
#define HDIM    64
#define QKV_N   (3*DMODEL)   // 1536

typedef short bf8  __attribute__((ext_vector_type(8)));   // 8 bf16 (4 VGPRs)
typedef float f32x4 __attribute__((ext_vector_type(4)));  // 4 fp32 acc

#define MFMA16(a,b,c) __builtin_amdgcn_mfma_f32_16x16x32_bf16((a),(b),(c),0,0,0)

__device__ inline unsigned short f2bf(float f){      // RNE fp32->bf16
  unsigned int u = __float_as_uint(f);
  u += 0x7FFFu + ((u >> 16) & 1u);
  return (unsigned short)(u >> 16);
}

// ---------------------------------------------------------------------------
// Fused prepass: cast x -> bf16 (blocks 0..2047), transpose+cast W_qkv
// (blocks 2048..2239), transpose+cast W_out (blocks 2240..2303).
// ---------------------------------------------------------------------------
__global__ __launch_bounds__(256) void prep(
    const float* __restrict__ x, const float* __restrict__ Wqkv,
    const float* __restrict__ Wout, unsigned short* __restrict__ Xh,
    unsigned short* __restrict__ WqkvT, unsigned short* __restrict__ WoutT)
{
  __shared__ unsigned short Ts[64][72];
  const int t = threadIdx.x;
  const int bx = blockIdx.x;
  if (bx < 2048) {
    const int i = bx*256 + t;
    const float4 a = reinterpret_cast<const float4*>(x)[2*i];
    const float4 b = reinterpret_cast<const float4*>(x)[2*i+1];
    uint4 o; unsigned short* us = reinterpret_cast<unsigned short*>(&o);
    us[0]=f2bf(a.x); us[1]=f2bf(a.y); us[2]=f2bf(a.z); us[3]=f2bf(a.w);
    us[4]=f2bf(b.x); us[5]=f2bf(b.y); us[6]=f2bf(b.z); us[7]=f2bf(b.w);
    reinterpret_cast<uint4*>(Xh)[i] = o;
    return;
  }
  const float* in; unsigned short* out; int R, C, gx, gy;
  if (bx < 2048 + 192) {
    const int bid = bx - 2048;
    gx = bid % 24; gy = bid / 24; in = Wqkv; out = WqkvT; R = DMODEL; C = QKV_N;
  } else {
    const int bid = bx - 2240;
    gx = bid % 8;  gy = bid / 8;  in = Wout; out = WoutT; R = DMODEL; C = DMODEL;
  }
  const int r0 = gy<<6, c0 = gx<<6;
  const int rr = t>>2, cs = (t&3)<<4;
#pragma unroll
  for (int p=0;p<4;++p){
    float4 v = *reinterpret_cast<const float4*>(in + (size_t)(r0+rr)*C + c0 + cs + p*4);
    Ts[rr][cs+p*4+0]=f2bf(v.x); Ts[rr][cs+p*4+1]=f2bf(v.y);
    Ts[rr][cs+p*4+2]=f2bf(v.z); Ts[rr][cs+p*4+3]=f2bf(v.w);
  }
  __syncthreads();
  const int cc = t>>2, rs = (t&3)<<4;
#pragma unroll
  for (int p=0;p<4;++p){
    ushort4 o;
    o.x = Ts[rs+p*4+0][cc]; o.y = Ts[rs+p*4+1][cc];
    o.z = Ts[rs+p*4+2][cc]; o.w = Ts[rs+p*4+3][cc];
    *reinterpret_cast<ushort4*>(out + (size_t)(c0+cc)*R + r0 + rs + p*4) = o;
  }
}

// ---------------------------------------------------------------------------
// MFMA GEMM A: QKV = Xh @ WqkvT^T  -> natural layout [8192][1536] bf16.
// B-frags permuted (row wc+4*l15+nj) so each lane's 4 C-columns are adjacent
// -> one 8B packed store per (mi,i); exact write traffic.
// Q-part columns (c%192 < 64) pre-scaled by 0.125.
// ---------------------------------------------------------------------------
__global__ __launch_bounds__(256) void gemm_qkv_mfma(
    const unsigned short* __restrict__ A, const unsigned short* __restrict__ Bt,
    unsigned short* __restrict__ QKV)
{
  __shared__ unsigned short As[128][72];
  __shared__ unsigned short Bs[128][72];
  const int t = threadIdx.x;
  const int w = t>>6, lane = t&63, quad = lane>>4, l15 = lane&15;
  const int wr = (w>>1)<<6, wc = (w&1)<<6;
  const int m0 = blockIdx.y<<7, n0 = blockIdx.x<<7;
  const int row = t>>3, seg = t&7;
  const unsigned short* Agp = A  + (size_t)(m0+row)*DMODEL + seg*8;
  const unsigned short* Bgp = Bt + (size_t)(n0+row)*DMODEL + seg*8;
  uint4 ga[4], gb[4];
#pragma unroll
  for (int p=0;p<4;++p){
    ga[p] = *reinterpret_cast<const uint4*>(Agp + (size_t)p*32*DMODEL);
    gb[p] = *reinterpret_cast<const uint4*>(Bgp + (size_t)p*32*DMODEL);
  }
  f32x4 acc[4][4];
#pragma unroll
  for (int i=0;i<4;++i)
#pragma unroll
    for (int j=0;j<4;++j) acc[i][j] = (f32x4){0.f,0.f,0.f,0.f};

  for (int k0=0;k0<DMODEL;k0+=64){
    __syncthreads();
#pragma unroll
    for (int p=0;p<4;++p){
      *reinterpret_cast<uint4*>(&As[row+p*32][seg*8]) = ga[p];
      *reinterpret_cast<uint4*>(&Bs[row+p*32][seg*8]) = gb[p];
    }
    __syncthreads();
    if (k0+64 < DMODEL){
#pragma unroll
      for (int p=0;p<4;++p){
        ga[p] = *reinterpret_cast<const uint4*>(Agp + (size_t)p*32*DMODEL + k0+64);
        gb[p] = *reinterpret_cast<const uint4*>(Bgp + (size_t)p*32*DMODEL + k0+64);
      }
    }
#pragma unroll
    for (int ks=0;ks<2;++ks){
      bf8 af[4], bfr[4];
#pragma unroll
      for (int mi=0;mi<4;++mi)
        af[mi]  = *reinterpret_cast<const bf8*>(&As[wr+mi*16+l15][ks*32+quad*8]);
#pragma unroll
      for (int nj=0;nj<4;++nj)
        bfr[nj] = *reinterpret_cast<const bf8*>(&Bs[wc+(l15<<2)+nj][ks*32+quad*8]);
#pragma unroll
      for (int mi=0;mi<4;++mi)
#pragma unroll
        for (int nj=0;nj<4;++nj) acc[mi][nj] = MFMA16(af[mi], bfr[nj], acc[mi][nj]);
    }
  }
  const int cbase = n0 + wc + (l15<<2);
  // scale flags for the 4 adjacent columns (Q-part?)
  bool isq[4];
#pragma unroll
  for (int nj=0;nj<4;++nj) isq[nj] = ((cbase+nj) % 192) < 64;
#pragma unroll
  for (int mi=0;mi<4;++mi)
#pragma unroll
    for (int i=0;i<4;++i){
      const int m = m0 + wr + mi*16 + quad*4 + i;
      unsigned long long pk = 0;
#pragma unroll
      for (int nj=0;nj<4;++nj){
        float v = acc[mi][nj][i];
        if (isq[nj]) v *= 0.125f;
        pk |= (unsigned long long)f2bf(v) << (16*nj);
      }
      *reinterpret_cast<unsigned long long*>(QKV + (size_t)m*QKV_N + cbase) = pk;
    }
}

// ---------------------------------------------------------------------------
// V^T builder: VT[bh][d][s] from natural qkv.
// V[b,h',kappa][d] = qkv[b*2048 + h'*256 + (kappa>>3)][(kappa&7)*192 + 128 + d]
// ---------------------------------------------------------------------------
__global__ __launch_bounds__(256) void v_transpose(
    const unsigned short* __restrict__ QKV, unsigned short* __restrict__ VT)
{
  __shared__ unsigned short Td[64][76];
  const int t = threadIdx.x;
  const int bh = blockIdx.y, b = bh>>3, hp = bh&7;
  const int s0 = blockIdx.x<<6;
  const size_t rbase = (size_t)(b*SEQ + hp*256);
  const int sr = t>>2, db = (t&3)<<4;
  const int kk = s0 + sr;
  const unsigned short* vp =
      QKV + (rbase + (kk>>3))*QKV_N + (kk&7)*192 + 128 + db;
  uint4 a = *reinterpret_cast<const uint4*>(vp);
  uint4 c = *reinterpret_cast<const uint4*>(vp + 8);
  const unsigned short* ua = reinterpret_cast<const unsigned short*>(&a);
  const unsigned short* uc = reinterpret_cast<const unsigned short*>(&c);
#pragma unroll
  for (int j=0;j<8;++j) Td[db+j][sr]   = ua[j];
#pragma unroll
  for (int j=0;j<8;++j) Td[db+8+j][sr] = uc[j];
  __syncthreads();
  const int L = t&15, d0 = t>>4;
  unsigned short* Op = VT + (size_t)bh*HDIM*SEQ + s0 + (L<<2);
#pragma unroll
  for (int cc=0;cc<4;++cc){
    const int d = d0 + (cc<<4);
    *reinterpret_cast<unsigned long long*>(Op + (size_t)d*SEQ) =
        *reinterpret_cast<const unsigned long long*>(&Td[d][L<<2]);
  }
}

// ---------------------------------------------------------------------------
// MFMA flash attention: Q/K read directly from natural qkv (slice address
// math implements the reference's flat-reinterpret scramble), LDS-staged
// K & V^T tiles, 32 queries/wave, no-max softmax, rho-permuted K staging.
// ---------------------------------------------------------------------------
__global__ __launch_bounds__(256, 2) void attn_mfma(
    const unsigned short* __restrict__ QKV, const unsigned short* __restrict__ VT,
    const int* __restrict__ mask, unsigned short* __restrict__ O)
{
  __shared__ unsigned long long mbits[32];   // 2048-bit validity
  __shared__ unsigned short Ks[64][72];      // rho-permuted K tile [row][d]
  __shared__ unsigned short Vs[64][72];      // V^T tile [d][key]
  __shared__ unsigned short Pl[4][32][72];   // wave-private P [q][key]
  const int t = threadIdx.x;
  const int w = t>>6, lane = t&63, quad = lane>>4, l15 = lane&15;
  const int bh = blockIdx.y, b = bh>>3, hp = bh&7;
  const int q0 = blockIdx.x<<7;              // 128 queries per block
  const int qs = q0 + (w<<5);                // 32 per wave
  const int* mb = mask + b*SEQ;
  const f32x4 Z4 = {0.f,0.f,0.f,0.f};
#pragma unroll
  for (int i=0;i<8;++i){
    const unsigned long long bal = __ballot(mb[i*256 + t] != 0);
    if (lane == 0) mbits[i*4 + w] = bal;
  }

  const size_t rbase = (size_t)(b*SEQ + hp*256);   // qkv row base for this bh
  bf8 qf[2][2];
#pragma unroll
  for (int a=0;a<2;++a){
    const int q = qs + a*16 + l15;
    const unsigned short* qp =
        QKV + (rbase + (q>>3))*QKV_N + (q&7)*192 + (quad<<3);
    qf[a][0] = *reinterpret_cast<const bf8*>(qp);
    qf[a][1] = *reinterpret_cast<const bf8*>(qp + 32);
  }
  const unsigned short* Vg = VT + (size_t)bh*HDIM*SEQ;

  const int srow = t>>2, sc4 = (t&3)<<4;             // staging: key row, col
  const int krow = ((srow&3)<<4) + (srow>>2);        // rho(srow)

  f32x4 of[2][4]; float lsum[2][4];
#pragma unroll
  for (int a=0;a<2;++a)
#pragma unroll
    for (int i=0;i<4;++i){ of[a][i]=Z4; lsum[a][i]=0.f; }

  __syncthreads();                                   // mbits visible

  for (int kt=0; kt<SEQ; kt+=64){
    // coalesced-ish global loads for staging (issued before barrier)
    const int kk = kt + srow;
    const unsigned short* kp =
        QKV + (rbase + (kk>>3))*QKV_N + (kk&7)*192 + 64 + sc4;
    const uint4 gk0 = *reinterpret_cast<const uint4*>(kp);
    const uint4 gk1 = *reinterpret_cast<const uint4*>(kp + 8);
    const unsigned short* vp = Vg + (size_t)srow*SEQ + kt + sc4;
    const uint4 gv0 = *reinterpret_cast<const uint4*>(vp);
    const uint4 gv1 = *reinterpret_cast<const uint4*>(vp + 8);
    __syncthreads();                                 // prev-tile readers done
    *reinterpret_cast<uint4*>(&Ks[krow][sc4])     = gk0;
    *reinterpret_cast<uint4*>(&Ks[krow][sc4+8])   = gk1;
    *reinterpret_cast<uint4*>(&Vs[srow][sc4])     = gv0;
    *reinterpret_cast<uint4*>(&Vs[srow][sc4+8])   = gv1;
    __syncthreads();                                 // tiles visible

    const unsigned int msel =
        (unsigned int)(mbits[kt>>6] >> (l15<<2)) & 0xFu;

    bf8 kf[4][2];
#pragma unroll
    for (int nf=0;nf<4;++nf){
      kf[nf][0] = *reinterpret_cast<const bf8*>(&Ks[nf*16+l15][quad<<3]);
      kf[nf][1] = *reinterpret_cast<const bf8*>(&Ks[nf*16+l15][32+(quad<<3)]);
    }

#pragma unroll
    for (int a=0;a<2;++a){
      f32x4 sc[4];
#pragma unroll
      for (int nf=0;nf<4;++nf){
        f32x4 s = MFMA16(qf[a][0], kf[nf][0], Z4);
        sc[nf] = MFMA16(qf[a][1], kf[nf][1], s);
      }
      float pv[4][4];
#pragma unroll
      for (int nf=0;nf<4;++nf){
        const bool on = (msel >> nf) & 1u;
#pragma unroll
        for (int i=0;i<4;++i)
          pv[nf][i] = on ? __expf(sc[nf][i]) : 0.f;  // Q pre-scaled by 0.125
      }
#pragma unroll
      for (int i=0;i<4;++i)
        lsum[a][i] += (pv[0][i]+pv[1][i]) + (pv[2][i]+pv[3][i]);
#pragma unroll
      for (int i=0;i<4;++i){
        const unsigned int lo = (unsigned int)f2bf(pv[0][i]) | ((unsigned int)f2bf(pv[1][i])<<16);
        const unsigned int hi = (unsigned int)f2bf(pv[2][i]) | ((unsigned int)f2bf(pv[3][i])<<16);
        *reinterpret_cast<unsigned long long*>(&Pl[w][a*16+(quad<<2)+i][l15<<2]) =
            ((unsigned long long)hi<<32) | lo;
      }
    }

    bf8 pa[2][2];
#pragma unroll
    for (int a=0;a<2;++a){
      pa[a][0] = *reinterpret_cast<const bf8*>(&Pl[w][a*16+l15][quad<<3]);
      pa[a][1] = *reinterpret_cast<const bf8*>(&Pl[w][a*16+l15][32+(quad<<3)]);
    }
#pragma unroll
    for (int nf=0;nf<4;++nf){
      const bf8 v0 = *reinterpret_cast<const bf8*>(&Vs[nf*16+l15][quad<<3]);
      const bf8 v1 = *reinterpret_cast<const bf8*>(&Vs[nf*16+l15][32+(quad<<3)]);
#pragma unroll
      for (int a=0;a<2;++a){
        f32x4 o = MFMA16(pa[a][0], v0, of[a][nf]);
        of[a][nf] = MFMA16(pa[a][1], v1, o);
      }
    }
  }

#pragma unroll
  for (int a=0;a<2;++a)
#pragma unroll
    for (int i=0;i<4;++i){
      float s = lsum[a][i];
      s += __shfl_xor(s,1); s += __shfl_xor(s,2);
      s += __shfl_xor(s,4); s += __shfl_xor(s,8);
      lsum[a][i] = s;
    }
  unsigned short* Op = O + (size_t)bh*SEQ*HDIM;
#pragma unroll
  for (int a=0;a<2;++a){
    const unsigned long long qw = mbits[(qs + a*16) >> 6];
#pragma unroll
    for (int i=0;i<4;++i){
      const int q = qs + a*16 + (quad<<2) + i;
      const bool qv = (qw >> (q & 63)) & 1ull;
      const float inv = (qv && lsum[a][i] > 0.f) ? 1.f/lsum[a][i] : 0.f;
#pragma unroll
      for (int nf=0;nf<4;++nf)
        Op[(size_t)q*HDIM + (nf<<4) + l15] = f2bf(of[a][nf][i]*inv);
    }
  }
}

// ---------------------------------------------------------------------------
// MFMA GEMM C: out = Ob @ WoutT^T, fp32 output, float4 stores (permuted
// B-frags -> adjacent lane columns).
// ---------------------------------------------------------------------------
__global__ __launch_bounds__(256) void gemm_out_mfma(
    const unsigned short* __restrict__ A, const unsigned short* __restrict__ Bt,
    float* __restrict__ Out)
{
  __shared__ unsigned short As[128][72];
  __shared__ unsigned short Bs[128][72];
  const int t = threadIdx.x;
  const int w = t>>6, lane = t&63, quad = lane>>4, l15 = lane&15;
  const int wr = (w>>1)<<6, wc = (w&1)<<6;
  const int m0 = blockIdx.y<<7, n0 = blockIdx.x<<7;
  const int row = t>>3, seg = t&7;
  const unsigned short* Agp = A  + (size_t)(m0+row)*DMODEL + seg*8;
  const unsigned short* Bgp = Bt + (size_t)(n0+row)*DMODEL + seg*8;
  uint4 ga[4], gb[4];
#pragma unroll
  for (int p=0;p<4;++p){
    ga[p] = *reinterpret_cast<const uint4*>(Agp + (size_t)p*32*DMODEL);
    gb[p] = *reinterpret_cast<const uint4*>(Bgp + (size_t)p*32*DMODEL);
  }
  f32x4 acc[4][4];
#pragma unroll
  for (int i=0;i<4;++i)
#pragma unroll
    for (int j=0;j<4;++j) acc[i][j] = (f32x4){0.f,0.f,0.f,0.f};

  for (int k0=0;k0<DMODEL;k0+=64){
    __syncthreads();
#pragma unroll
    for (int p=0;p<4;++p){
      *reinterpret_cast<uint4*>(&As[row+p*32][seg*8]) = ga[p];
      *reinterpret_cast<uint4*>(&Bs[row+p*32][seg*8]) = gb[p];
    }
    __syncthreads();
    if (k0+64 < DMODEL){
#pragma unroll
      for (int p=0;p<4;++p){
        ga[p] = *reinterpret_cast<const uint4*>(Agp + (size_t)p*32*DMODEL + k0+64);
        gb[p] = *reinterpret_cast<const uint4*>(Bgp + (size_t)p*32*DMODEL + k0+64);
      }
    }
#pragma unroll
    for (int ks=0;ks<2;++ks){
      bf8 af[4], bfr[4];
#pragma unroll
      for (int mi=0;mi<4;++mi)
        af[mi]  = *reinterpret_cast<const bf8*>(&As[wr+mi*16+l15][ks*32+quad*8]);
#pragma unroll
      for (int nj=0;nj<4;++nj)
        bfr[nj] = *reinterpret_cast<const bf8*>(&Bs[wc+(l15<<2)+nj][ks*32+quad*8]);
#pragma unroll
      for (int mi=0;mi<4;++mi)
#pragma unroll
        for (int nj=0;nj<4;++nj) acc[mi][nj] = MFMA16(af[mi], bfr[nj], acc[mi][nj]);
    }
  }
  const int cbase = n0 + wc + (l15<<2);
#pragma unroll
  for (int mi=0;mi<4;++mi)
#pragma unroll
    for (int i=0;i<4;++i){
      const int m = m0 + wr + mi*16 + quad*4 + i;
      const float4 o = make_float4(acc[mi][0][i], acc[mi][1][i],
                                   acc[mi][2][i], acc[mi][3][i]);
      *reinterpret_cast<float4*>(Out + (size_t)m*DMODEL + cbase) = o;
    }
}

// ---------------------------------------------------------------------------
extern "C" void kernel_launch(void* const* d_in, const int* in_sizes, int n_in,
                              void* d_out, int out_size, void* d_ws, size_t ws_size,
                              hipStream_t stream) {
  (void)in_sizes; (void)n_in; (void)out_size; (void)ws_size;
  const float* x     = (const float*)d_in[0];
  const int*   pmask = (const int*)d_in[2];
  const float* Wqkv  = (const float*)d_in[3];
  const float* Wout  = (const float*)d_in[4];
  float* out = (float*)d_out;

  const size_t per = (size_t)BATCH*NHEADS*SEQ*HDIM;     // 4,194,304
  unsigned short* Xh    = (unsigned short*)d_ws;        // 4.19M
  unsigned short* WqkvT = Xh    + (size_t)8192*512;     // 0.79M
  unsigned short* WoutT = WqkvT + (size_t)1536*512;     // 0.26M
  unsigned short* QKVb  = WoutT + (size_t)512*512;      // 12.58M
  unsigned short* VbT   = QKVb  + (size_t)8192*QKV_N;   // 4.19M
  unsigned short* Ob    = VbT + per;                    // 4.19M  (~52 MB total)

  prep<<<2304, 256, 0, stream>>>(x, Wqkv, Wout, Xh, WqkvT, WoutT);
  gemm_qkv_mfma<<<dim3(QKV_N/128, 8192/128), 256, 0, stream>>>(Xh, WqkvT, QKVb);
  v_transpose<<<dim3(SEQ/64, BATCH*NHEADS), 256, 0, stream>>>(QKVb, VbT);
  attn_mfma<<<dim3(SEQ/128, BATCH*NHEADS), 256, 0, stream>>>(QKVb, VbT, pmask, Ob);
  gemm_out_mfma<<<dim3(DMODEL/128, 8192/128), 256, 0, stream>>>(Ob, WoutT, out);
}

// Round 7
// 204.801 us; speedup vs baseline: 2.0520x; 1.2398x over previous
//
#include <hip/hip_runtime.h>
#include <math.h>
#include <stdint.h>

#define BATCH   4
#define SEQ     2048
#define DMODEL  512
#define NHEADS  8
#define HDIM    64
#define QKV_N   (3*DMODEL)   // 1536

typedef short bf8  __attribute__((ext_vector_type(8)));   // 8 bf16 (4 VGPRs)
typedef float f32x4 __attribute__((ext_vector_type(4)));  // 4 fp32 acc

#define MFMA16(a,b,c) __builtin_amdgcn_mfma_f32_16x16x32_bf16((a),(b),(c),0,0,0)

__device__ inline unsigned short f2bf(float f){      // RNE fp32->bf16
  unsigned int u = __float_as_uint(f);
  u += 0x7FFFu + ((u >> 16) & 1u);
  return (unsigned short)(u >> 16);
}

// global -> LDS direct DMA, 16 B per lane. LDS dest = wave-uniform base +
// lane*16 (so the LDS tile must be unpadded, in lane order).
__device__ __forceinline__ void gload_lds16(const unsigned short* g,
                                            unsigned short* l){
  __builtin_amdgcn_global_load_lds(
      (const __attribute__((address_space(1))) unsigned int*)g,
      (__attribute__((address_space(3))) unsigned int*)l,
      16, 0, 0);
}

// ---------------------------------------------------------------------------
// Fused prepass: cast x -> bf16 (blocks 0..2047), transpose+cast W_qkv
// (blocks 2048..2239), transpose+cast W_out (blocks 2240..2303).
// ---------------------------------------------------------------------------
__global__ __launch_bounds__(256) void prep(
    const float* __restrict__ x, const float* __restrict__ Wqkv,
    const float* __restrict__ Wout, unsigned short* __restrict__ Xh,
    unsigned short* __restrict__ WqkvT, unsigned short* __restrict__ WoutT)
{
  __shared__ unsigned short Ts[64][72];
  const int t = threadIdx.x;
  const int bx = blockIdx.x;
  if (bx < 2048) {
    const int i = bx*256 + t;
    const float4 a = reinterpret_cast<const float4*>(x)[2*i];
    const float4 b = reinterpret_cast<const float4*>(x)[2*i+1];
    uint4 o; unsigned short* us = reinterpret_cast<unsigned short*>(&o);
    us[0]=f2bf(a.x); us[1]=f2bf(a.y); us[2]=f2bf(a.z); us[3]=f2bf(a.w);
    us[4]=f2bf(b.x); us[5]=f2bf(b.y); us[6]=f2bf(b.z); us[7]=f2bf(b.w);
    reinterpret_cast<uint4*>(Xh)[i] = o;
    return;
  }
  const float* in; unsigned short* out; int R, C, gx, gy;
  if (bx < 2048 + 192) {
    const int bid = bx - 2048;
    gx = bid % 24; gy = bid / 24; in = Wqkv; out = WqkvT; R = DMODEL; C = QKV_N;
  } else {
    const int bid = bx - 2240;
    gx = bid % 8;  gy = bid / 8;  in = Wout; out = WoutT; R = DMODEL; C = DMODEL;
  }
  const int r0 = gy<<6, c0 = gx<<6;
  const int rr = t>>2, cs = (t&3)<<4;
#pragma unroll
  for (int p=0;p<4;++p){
    float4 v = *reinterpret_cast<const float4*>(in + (size_t)(r0+rr)*C + c0 + cs + p*4);
    Ts[rr][cs+p*4+0]=f2bf(v.x); Ts[rr][cs+p*4+1]=f2bf(v.y);
    Ts[rr][cs+p*4+2]=f2bf(v.z); Ts[rr][cs+p*4+3]=f2bf(v.w);
  }
  __syncthreads();
  const int cc = t>>2, rs = (t&3)<<4;
#pragma unroll
  for (int p=0;p<4;++p){
    ushort4 o;
    o.x = Ts[rs+p*4+0][cc]; o.y = Ts[rs+p*4+1][cc];
    o.z = Ts[rs+p*4+2][cc]; o.w = Ts[rs+p*4+3][cc];
    *reinterpret_cast<ushort4*>(out + (size_t)(c0+cc)*R + r0 + rs + p*4) = o;
  }
}

// ---------------------------------------------------------------------------
// MFMA GEMM A (m97 structure): QKV = Xh @ WqkvT^T -> natural [8192][1536].
// global_load_lds width-16 staging into UNPADDED [128][64] tiles; 2-barrier
// K-loop; permuted B-frags -> adjacent lane columns -> 8B packed stores.
// Q-part columns (c%192 < 64) pre-scaled by 0.125.
// ---------------------------------------------------------------------------
__global__ __launch_bounds__(256) void gemm_qkv_mfma(
    const unsigned short* __restrict__ A, const unsigned short* __restrict__ Bt,
    unsigned short* __restrict__ QKV)
{
  __shared__ unsigned short As[128][64];
  __shared__ unsigned short Bs[128][64];
  const int t = threadIdx.x;
  const int w = t>>6, lane = t&63, quad = lane>>4, l15 = lane&15;
  const int wr = (w>>1)<<6, wc = (w&1)<<6;
  const int m0 = blockIdx.y<<7, n0 = blockIdx.x<<7;
  const int row = t>>3, seg = t&7;          // row = w*8 + (lane>>3), seg = lane&7
  const unsigned short* Agp = A  + (size_t)(m0+row)*DMODEL + seg*8;
  const unsigned short* Bgp = Bt + (size_t)(n0+row)*DMODEL + seg*8;
  f32x4 acc[4][4];
#pragma unroll
  for (int i=0;i<4;++i)
#pragma unroll
    for (int j=0;j<4;++j) acc[i][j] = (f32x4){0.f,0.f,0.f,0.f};

  for (int k0=0;k0<DMODEL;k0+=64){
    __syncthreads();                         // prev-tile readers done
#pragma unroll
    for (int p=0;p<4;++p){
      gload_lds16(Agp + (size_t)p*32*DMODEL + k0, &As[(w<<3)+(p<<5)][0]);
      gload_lds16(Bgp + (size_t)p*32*DMODEL + k0, &Bs[(w<<3)+(p<<5)][0]);
    }
    __syncthreads();                         // vmcnt(0) drain + visibility
#pragma unroll
    for (int ks=0;ks<2;++ks){
      bf8 af[4], bfr[4];
#pragma unroll
      for (int mi=0;mi<4;++mi)
        af[mi]  = *reinterpret_cast<const bf8*>(&As[wr+mi*16+l15][ks*32+quad*8]);
#pragma unroll
      for (int nj=0;nj<4;++nj)
        bfr[nj] = *reinterpret_cast<const bf8*>(&Bs[wc+(l15<<2)+nj][ks*32+quad*8]);
#pragma unroll
      for (int mi=0;mi<4;++mi)
#pragma unroll
        for (int nj=0;nj<4;++nj) acc[mi][nj] = MFMA16(af[mi], bfr[nj], acc[mi][nj]);
    }
  }
  const int cbase = n0 + wc + (l15<<2);
  bool isq[4];
#pragma unroll
  for (int nj=0;nj<4;++nj) isq[nj] = ((cbase+nj) % 192) < 64;
#pragma unroll
  for (int mi=0;mi<4;++mi)
#pragma unroll
    for (int i=0;i<4;++i){
      const int m = m0 + wr + mi*16 + quad*4 + i;
      unsigned long long pk = 0;
#pragma unroll
      for (int nj=0;nj<4;++nj){
        float v = acc[mi][nj][i];
        if (isq[nj]) v *= 0.125f;
        pk |= (unsigned long long)f2bf(v) << (16*nj);
      }
      *reinterpret_cast<unsigned long long*>(QKV + (size_t)m*QKV_N + cbase) = pk;
    }
}

// ---------------------------------------------------------------------------
// V^T builder: VT[bh][d][s] from natural qkv.
// V[b,h',kappa][d] = qkv[b*2048 + h'*256 + (kappa>>3)][(kappa&7)*192 + 128 + d]
// ---------------------------------------------------------------------------
__global__ __launch_bounds__(256) void v_transpose(
    const unsigned short* __restrict__ QKV, unsigned short* __restrict__ VT)
{
  __shared__ unsigned short Td[64][76];
  const int t = threadIdx.x;
  const int bh = blockIdx.y, b = bh>>3, hp = bh&7;
  const int s0 = blockIdx.x<<6;
  const size_t rbase = (size_t)(b*SEQ + hp*256);
  const int sr = t>>2, db = (t&3)<<4;
  const int kk = s0 + sr;
  const unsigned short* vp =
      QKV + (rbase + (kk>>3))*QKV_N + (kk&7)*192 + 128 + db;
  uint4 a = *reinterpret_cast<const uint4*>(vp);
  uint4 c = *reinterpret_cast<const uint4*>(vp + 8);
  const unsigned short* ua = reinterpret_cast<const unsigned short*>(&a);
  const unsigned short* uc = reinterpret_cast<const unsigned short*>(&c);
#pragma unroll
  for (int j=0;j<8;++j) Td[db+j][sr]   = ua[j];
#pragma unroll
  for (int j=0;j<8;++j) Td[db+8+j][sr] = uc[j];
  __syncthreads();
  const int L = t&15, d0 = t>>4;
  unsigned short* Op = VT + (size_t)bh*HDIM*SEQ + s0 + (L<<2);
#pragma unroll
  for (int cc=0;cc<4;++cc){
    const int d = d0 + (cc<<4);
    *reinterpret_cast<unsigned long long*>(Op + (size_t)d*SEQ) =
        *reinterpret_cast<const unsigned long long*>(&Td[d][L<<2]);
  }
}

// ---------------------------------------------------------------------------
// MFMA flash attention: Q/K read directly from natural qkv (slice address
// math implements the reference's flat-reinterpret scramble), LDS-staged
// K & V^T tiles, 32 queries/wave, no-max softmax, rho-permuted K staging.
// ---------------------------------------------------------------------------
__global__ __launch_bounds__(256, 2) void attn_mfma(
    const unsigned short* __restrict__ QKV, const unsigned short* __restrict__ VT,
    const int* __restrict__ mask, unsigned short* __restrict__ O)
{
  __shared__ unsigned long long mbits[32];   // 2048-bit validity
  __shared__ unsigned short Ks[64][72];      // rho-permuted K tile [row][d]
  __shared__ unsigned short Vs[64][72];      // V^T tile [d][key]
  __shared__ unsigned short Pl[4][32][72];   // wave-private P [q][key]
  const int t = threadIdx.x;
  const int w = t>>6, lane = t&63, quad = lane>>4, l15 = lane&15;
  const int bh = blockIdx.y, b = bh>>3, hp = bh&7;
  const int q0 = blockIdx.x<<7;              // 128 queries per block
  const int qs = q0 + (w<<5);                // 32 per wave
  const int* mb = mask + b*SEQ;
  const f32x4 Z4 = {0.f,0.f,0.f,0.f};
#pragma unroll
  for (int i=0;i<8;++i){
    const unsigned long long bal = __ballot(mb[i*256 + t] != 0);
    if (lane == 0) mbits[i*4 + w] = bal;
  }

  const size_t rbase = (size_t)(b*SEQ + hp*256);   // qkv row base for this bh
  bf8 qf[2][2];
#pragma unroll
  for (int a=0;a<2;++a){
    const int q = qs + a*16 + l15;
    const unsigned short* qp =
        QKV + (rbase + (q>>3))*QKV_N + (q&7)*192 + (quad<<3);
    qf[a][0] = *reinterpret_cast<const bf8*>(qp);
    qf[a][1] = *reinterpret_cast<const bf8*>(qp + 32);
  }
  const unsigned short* Vg = VT + (size_t)bh*HDIM*SEQ;

  const int srow = t>>2, sc4 = (t&3)<<4;             // staging: key row, col
  const int krow = ((srow&3)<<4) + (srow>>2);        // rho(srow)

  f32x4 of[2][4]; float lsum[2][4];
#pragma unroll
  for (int a=0;a<2;++a)
#pragma unroll
    for (int i=0;i<4;++i){ of[a][i]=Z4; lsum[a][i]=0.f; }

  __syncthreads();                                   // mbits visible

  for (int kt=0; kt<SEQ; kt+=64){
    const int kk = kt + srow;
    const unsigned short* kp =
        QKV + (rbase + (kk>>3))*QKV_N + (kk&7)*192 + 64 + sc4;
    const uint4 gk0 = *reinterpret_cast<const uint4*>(kp);
    const uint4 gk1 = *reinterpret_cast<const uint4*>(kp + 8);
    const unsigned short* vp = Vg + (size_t)srow*SEQ + kt + sc4;
    const uint4 gv0 = *reinterpret_cast<const uint4*>(vp);
    const uint4 gv1 = *reinterpret_cast<const uint4*>(vp + 8);
    __syncthreads();                                 // prev-tile readers done
    *reinterpret_cast<uint4*>(&Ks[krow][sc4])     = gk0;
    *reinterpret_cast<uint4*>(&Ks[krow][sc4+8])   = gk1;
    *reinterpret_cast<uint4*>(&Vs[srow][sc4])     = gv0;
    *reinterpret_cast<uint4*>(&Vs[srow][sc4+8])   = gv1;
    __syncthreads();                                 // tiles visible

    const unsigned int msel =
        (unsigned int)(mbits[kt>>6] >> (l15<<2)) & 0xFu;

    bf8 kf[4][2];
#pragma unroll
    for (int nf=0;nf<4;++nf){
      kf[nf][0] = *reinterpret_cast<const bf8*>(&Ks[nf*16+l15][quad<<3]);
      kf[nf][1] = *reinterpret_cast<const bf8*>(&Ks[nf*16+l15][32+(quad<<3)]);
    }

#pragma unroll
    for (int a=0;a<2;++a){
      f32x4 sc[4];
#pragma unroll
      for (int nf=0;nf<4;++nf){
        f32x4 s = MFMA16(qf[a][0], kf[nf][0], Z4);
        sc[nf] = MFMA16(qf[a][1], kf[nf][1], s);
      }
      float pv[4][4];
#pragma unroll
      for (int nf=0;nf<4;++nf){
        const bool on = (msel >> nf) & 1u;
#pragma unroll
        for (int i=0;i<4;++i)
          pv[nf][i] = on ? __expf(sc[nf][i]) : 0.f;  // Q pre-scaled by 0.125
      }
#pragma unroll
      for (int i=0;i<4;++i)
        lsum[a][i] += (pv[0][i]+pv[1][i]) + (pv[2][i]+pv[3][i]);
#pragma unroll
      for (int i=0;i<4;++i){
        const unsigned int lo = (unsigned int)f2bf(pv[0][i]) | ((unsigned int)f2bf(pv[1][i])<<16);
        const unsigned int hi = (unsigned int)f2bf(pv[2][i]) | ((unsigned int)f2bf(pv[3][i])<<16);
        *reinterpret_cast<unsigned long long*>(&Pl[w][a*16+(quad<<2)+i][l15<<2]) =
            ((unsigned long long)hi<<32) | lo;
      }
    }

    bf8 pa[2][2];
#pragma unroll
    for (int a=0;a<2;++a){
      pa[a][0] = *reinterpret_cast<const bf8*>(&Pl[w][a*16+l15][quad<<3]);
      pa[a][1] = *reinterpret_cast<const bf8*>(&Pl[w][a*16+l15][32+(quad<<3)]);
    }
#pragma unroll
    for (int nf=0;nf<4;++nf){
      const bf8 v0 = *reinterpret_cast<const bf8*>(&Vs[nf*16+l15][quad<<3]);
      const bf8 v1 = *reinterpret_cast<const bf8*>(&Vs[nf*16+l15][32+(quad<<3)]);
#pragma unroll
      for (int a=0;a<2;++a){
        f32x4 o = MFMA16(pa[a][0], v0, of[a][nf]);
        of[a][nf] = MFMA16(pa[a][1], v1, o);
      }
    }
  }

#pragma unroll
  for (int a=0;a<2;++a)
#pragma unroll
    for (int i=0;i<4;++i){
      float s = lsum[a][i];
      s += __shfl_xor(s,1); s += __shfl_xor(s,2);
      s += __shfl_xor(s,4); s += __shfl_xor(s,8);
      lsum[a][i] = s;
    }
  unsigned short* Op = O + (size_t)bh*SEQ*HDIM;
#pragma unroll
  for (int a=0;a<2;++a){
    const unsigned long long qw = mbits[(qs + a*16) >> 6];
#pragma unroll
    for (int i=0;i<4;++i){
      const int q = qs + a*16 + (quad<<2) + i;
      const bool qv = (qw >> (q & 63)) & 1ull;
      const float inv = (qv && lsum[a][i] > 0.f) ? 1.f/lsum[a][i] : 0.f;
#pragma unroll
      for (int nf=0;nf<4;++nf)
        Op[(size_t)q*HDIM + (nf<<4) + l15] = f2bf(of[a][nf][i]*inv);
    }
  }
}

// ---------------------------------------------------------------------------
// MFMA GEMM C (m97 structure): out = Ob @ WoutT^T, fp32 float4 stores.
// ---------------------------------------------------------------------------
__global__ __launch_bounds__(256) void gemm_out_mfma(
    const unsigned short* __restrict__ A, const unsigned short* __restrict__ Bt,
    float* __restrict__ Out)
{
  __shared__ unsigned short As[128][64];
  __shared__ unsigned short Bs[128][64];
  const int t = threadIdx.x;
  const int w = t>>6, lane = t&63, quad = lane>>4, l15 = lane&15;
  const int wr = (w>>1)<<6, wc = (w&1)<<6;
  const int m0 = blockIdx.y<<7, n0 = blockIdx.x<<7;
  const int row = t>>3, seg = t&7;
  const unsigned short* Agp = A  + (size_t)(m0+row)*DMODEL + seg*8;
  const unsigned short* Bgp = Bt + (size_t)(n0+row)*DMODEL + seg*8;
  f32x4 acc[4][4];
#pragma unroll
  for (int i=0;i<4;++i)
#pragma unroll
    for (int j=0;j<4;++j) acc[i][j] = (f32x4){0.f,0.f,0.f,0.f};

  for (int k0=0;k0<DMODEL;k0+=64){
    __syncthreads();
#pragma unroll
    for (int p=0;p<4;++p){
      gload_lds16(Agp + (size_t)p*32*DMODEL + k0, &As[(w<<3)+(p<<5)][0]);
      gload_lds16(Bgp + (size_t)p*32*DMODEL + k0, &Bs[(w<<3)+(p<<5)][0]);
    }
    __syncthreads();
#pragma unroll
    for (int ks=0;ks<2;++ks){
      bf8 af[4], bfr[4];
#pragma unroll
      for (int mi=0;mi<4;++mi)
        af[mi]  = *reinterpret_cast<const bf8*>(&As[wr+mi*16+l15][ks*32+quad*8]);
#pragma unroll
      for (int nj=0;nj<4;++nj)
        bfr[nj] = *reinterpret_cast<const bf8*>(&Bs[wc+(l15<<2)+nj][ks*32+quad*8]);
#pragma unroll
      for (int mi=0;mi<4;++mi)
#pragma unroll
        for (int nj=0;nj<4;++nj) acc[mi][nj] = MFMA16(af[mi], bfr[nj], acc[mi][nj]);
    }
  }
  const int cbase = n0 + wc + (l15<<2);
#pragma unroll
  for (int mi=0;mi<4;++mi)
#pragma unroll
    for (int i=0;i<4;++i){
      const int m = m0 + wr + mi*16 + quad*4 + i;
      const float4 o = make_float4(acc[mi][0][i], acc[mi][1][i],
                                   acc[mi][2][i], acc[mi][3][i]);
      *reinterpret_cast<float4*>(Out + (size_t)m*DMODEL + cbase) = o;
    }
}

// ---------------------------------------------------------------------------
extern "C" void kernel_launch(void* const* d_in, const int* in_sizes, int n_in,
                              void* d_out, int out_size, void* d_ws, size_t ws_size,
                              hipStream_t stream) {
  (void)in_sizes; (void)n_in; (void)out_size; (void)ws_size;
  const float* x     = (const float*)d_in[0];
  const int*   pmask = (const int*)d_in[2];
  const float* Wqkv  = (const float*)d_in[3];
  const float* Wout  = (const float*)d_in[4];
  float* out = (float*)d_out;

  const size_t per = (size_t)BATCH*NHEADS*SEQ*HDIM;     // 4,194,304
  unsigned short* Xh    = (unsigned short*)d_ws;        // 4.19M
  unsigned short* WqkvT = Xh    + (size_t)8192*512;     // 0.79M
  unsigned short* WoutT = WqkvT + (size_t)1536*512;     // 0.26M
  unsigned short* QKVb  = WoutT + (size_t)512*512;      // 12.58M
  unsigned short* VbT   = QKVb  + (size_t)8192*QKV_N;   // 4.19M
  unsigned short* Ob    = VbT + per;                    // 4.19M  (~52 MB total)

  prep<<<2304, 256, 0, stream>>>(x, Wqkv, Wout, Xh, WqkvT, WoutT);
  gemm_qkv_mfma<<<dim3(QKV_N/128, 8192/128), 256, 0, stream>>>(Xh, WqkvT, QKVb);
  v_transpose<<<dim3(SEQ/64, BATCH*NHEADS), 256, 0, stream>>>(QKVb, VbT);
  attn_mfma<<<dim3(SEQ/128, BATCH*NHEADS), 256, 0, stream>>>(QKVb, VbT, pmask, Ob);
  gemm_out_mfma<<<dim3(DMODEL/128, 8192/128), 256, 0, stream>>>(Ob, WoutT, out);
}

// Round 8
// 196.586 us; speedup vs baseline: 2.1378x; 1.0418x over previous
//
#include <hip/hip_runtime.h>
#include <hip/hip_bf16.h>
#include <math.h>
#include <stdint.h>

#define BATCH   4
#define SEQ     2048
#define DMODEL  512
#define NHEADS  8
#define HDIM    64
#define QKV_N   (3*DMODEL)   // 1536

typedef short bf8  __attribute__((ext_vector_type(8)));   // 8 bf16 (4 VGPRs)
typedef float f32x4 __attribute__((ext_vector_type(4)));  // 4 fp32 acc

#define MFMA16(a,b,c) __builtin_amdgcn_mfma_f32_16x16x32_bf16((a),(b),(c),0,0,0)

__device__ inline unsigned short f2bf(float f){      // RNE fp32->bf16
  unsigned int u = __float_as_uint(f);
  u += 0x7FFFu + ((u >> 16) & 1u);
  return (unsigned short)(u >> 16);
}

__device__ inline unsigned int pack_bf2(float a, float b){  // v_cvt_pk_bf16_f32
  __hip_bfloat162 h = __float22bfloat162_rn(make_float2(a, b));
  return *reinterpret_cast<unsigned int*>(&h);
}

// global -> LDS direct DMA, 16 B per lane. LDS dest = wave-uniform base +
// lane*16 (so the LDS tile must be unpadded, in lane order).
__device__ __forceinline__ void gload_lds16(const unsigned short* g,
                                            unsigned short* l){
  __builtin_amdgcn_global_load_lds(
      (const __attribute__((address_space(1))) unsigned int*)g,
      (__attribute__((address_space(3))) unsigned int*)l,
      16, 0, 0);
}

// ---------------------------------------------------------------------------
// Fused prepass: cast x -> bf16 (blocks 0..2047), transpose+cast W_qkv
// (blocks 2048..2239), transpose+cast W_out (blocks 2240..2303).
// ---------------------------------------------------------------------------
__global__ __launch_bounds__(256) void prep(
    const float* __restrict__ x, const float* __restrict__ Wqkv,
    const float* __restrict__ Wout, unsigned short* __restrict__ Xh,
    unsigned short* __restrict__ WqkvT, unsigned short* __restrict__ WoutT)
{
  __shared__ unsigned short Ts[64][72];
  const int t = threadIdx.x;
  const int bx = blockIdx.x;
  if (bx < 2048) {
    const int i = bx*256 + t;
    const float4 a = reinterpret_cast<const float4*>(x)[2*i];
    const float4 b = reinterpret_cast<const float4*>(x)[2*i+1];
    uint4 o; unsigned short* us = reinterpret_cast<unsigned short*>(&o);
    us[0]=f2bf(a.x); us[1]=f2bf(a.y); us[2]=f2bf(a.z); us[3]=f2bf(a.w);
    us[4]=f2bf(b.x); us[5]=f2bf(b.y); us[6]=f2bf(b.z); us[7]=f2bf(b.w);
    reinterpret_cast<uint4*>(Xh)[i] = o;
    return;
  }
  const float* in; unsigned short* out; int R, C, gx, gy;
  if (bx < 2048 + 192) {
    const int bid = bx - 2048;
    gx = bid % 24; gy = bid / 24; in = Wqkv; out = WqkvT; R = DMODEL; C = QKV_N;
  } else {
    const int bid = bx - 2240;
    gx = bid % 8;  gy = bid / 8;  in = Wout; out = WoutT; R = DMODEL; C = DMODEL;
  }
  const int r0 = gy<<6, c0 = gx<<6;
  const int rr = t>>2, cs = (t&3)<<4;
#pragma unroll
  for (int p=0;p<4;++p){
    float4 v = *reinterpret_cast<const float4*>(in + (size_t)(r0+rr)*C + c0 + cs + p*4);
    Ts[rr][cs+p*4+0]=f2bf(v.x); Ts[rr][cs+p*4+1]=f2bf(v.y);
    Ts[rr][cs+p*4+2]=f2bf(v.z); Ts[rr][cs+p*4+3]=f2bf(v.w);
  }
  __syncthreads();
  const int cc = t>>2, rs = (t&3)<<4;
#pragma unroll
  for (int p=0;p<4;++p){
    ushort4 o;
    o.x = Ts[rs+p*4+0][cc]; o.y = Ts[rs+p*4+1][cc];
    o.z = Ts[rs+p*4+2][cc]; o.w = Ts[rs+p*4+3][cc];
    *reinterpret_cast<ushort4*>(out + (size_t)(c0+cc)*R + r0 + rs + p*4) = o;
  }
}

// ---------------------------------------------------------------------------
// MFMA GEMM A (m97 structure): QKV = Xh @ WqkvT^T -> natural [8192][1536].
// global_load_lds width-16 staging into UNPADDED [128][64] tiles; 2-barrier
// K-loop; permuted B-frags -> adjacent lane columns -> 8B packed stores.
// Q-part columns (c%192 < 64) pre-scaled by 0.125.
// ---------------------------------------------------------------------------
__global__ __launch_bounds__(256) void gemm_qkv_mfma(
    const unsigned short* __restrict__ A, const unsigned short* __restrict__ Bt,
    unsigned short* __restrict__ QKV)
{
  __shared__ unsigned short As[128][64];
  __shared__ unsigned short Bs[128][64];
  const int t = threadIdx.x;
  const int w = t>>6, lane = t&63, quad = lane>>4, l15 = lane&15;
  const int wr = (w>>1)<<6, wc = (w&1)<<6;
  const int m0 = blockIdx.y<<7, n0 = blockIdx.x<<7;
  const int row = t>>3, seg = t&7;
  const unsigned short* Agp = A  + (size_t)(m0+row)*DMODEL + seg*8;
  const unsigned short* Bgp = Bt + (size_t)(n0+row)*DMODEL + seg*8;
  f32x4 acc[4][4];
#pragma unroll
  for (int i=0;i<4;++i)
#pragma unroll
    for (int j=0;j<4;++j) acc[i][j] = (f32x4){0.f,0.f,0.f,0.f};

  for (int k0=0;k0<DMODEL;k0+=64){
    __syncthreads();
#pragma unroll
    for (int p=0;p<4;++p){
      gload_lds16(Agp + (size_t)p*32*DMODEL + k0, &As[(w<<3)+(p<<5)][0]);
      gload_lds16(Bgp + (size_t)p*32*DMODEL + k0, &Bs[(w<<3)+(p<<5)][0]);
    }
    __syncthreads();
#pragma unroll
    for (int ks=0;ks<2;++ks){
      bf8 af[4], bfr[4];
#pragma unroll
      for (int mi=0;mi<4;++mi)
        af[mi]  = *reinterpret_cast<const bf8*>(&As[wr+mi*16+l15][ks*32+quad*8]);
#pragma unroll
      for (int nj=0;nj<4;++nj)
        bfr[nj] = *reinterpret_cast<const bf8*>(&Bs[wc+(l15<<2)+nj][ks*32+quad*8]);
#pragma unroll
      for (int mi=0;mi<4;++mi)
#pragma unroll
        for (int nj=0;nj<4;++nj) acc[mi][nj] = MFMA16(af[mi], bfr[nj], acc[mi][nj]);
    }
  }
  const int cbase = n0 + wc + (l15<<2);
  bool isq[4];
#pragma unroll
  for (int nj=0;nj<4;++nj) isq[nj] = ((cbase+nj) % 192) < 64;
#pragma unroll
  for (int mi=0;mi<4;++mi)
#pragma unroll
    for (int i=0;i<4;++i){
      const int m = m0 + wr + mi*16 + quad*4 + i;
      unsigned long long pk = 0;
#pragma unroll
      for (int nj=0;nj<4;++nj){
        float v = acc[mi][nj][i];
        if (isq[nj]) v *= 0.125f;
        pk |= (unsigned long long)f2bf(v) << (16*nj);
      }
      *reinterpret_cast<unsigned long long*>(QKV + (size_t)m*QKV_N + cbase) = pk;
    }
}

// ---------------------------------------------------------------------------
// V^T builder: VT[bh][d][s] from natural qkv.
// ---------------------------------------------------------------------------
__global__ __launch_bounds__(256) void v_transpose(
    const unsigned short* __restrict__ QKV, unsigned short* __restrict__ VT)
{
  __shared__ unsigned short Td[64][76];
  const int t = threadIdx.x;
  const int bh = blockIdx.y, b = bh>>3, hp = bh&7;
  const int s0 = blockIdx.x<<6;
  const size_t rbase = (size_t)(b*SEQ + hp*256);
  const int sr = t>>2, db = (t&3)<<4;
  const int kk = s0 + sr;
  const unsigned short* vp =
      QKV + (rbase + (kk>>3))*QKV_N + (kk&7)*192 + 128 + db;
  uint4 a = *reinterpret_cast<const uint4*>(vp);
  uint4 c = *reinterpret_cast<const uint4*>(vp + 8);
  const unsigned short* ua = reinterpret_cast<const unsigned short*>(&a);
  const unsigned short* uc = reinterpret_cast<const unsigned short*>(&c);
#pragma unroll
  for (int j=0;j<8;++j) Td[db+j][sr]   = ua[j];
#pragma unroll
  for (int j=0;j<8;++j) Td[db+8+j][sr] = uc[j];
  __syncthreads();
  const int L = t&15, d0 = t>>4;
  unsigned short* Op = VT + (size_t)bh*HDIM*SEQ + s0 + (L<<2);
#pragma unroll
  for (int cc=0;cc<4;++cc){
    const int d = d0 + (cc<<4);
    *reinterpret_cast<unsigned long long*>(Op + (size_t)d*SEQ) =
        *reinterpret_cast<const unsigned long long*>(&Td[d][L<<2]);
  }
}

// ---------------------------------------------------------------------------
// MFMA flash attention v4: register double-buffered K/V staging (loads for
// tile t+1 issued before compute of tile t), LDS-shared tiles, 32 q/wave,
// no-max softmax, rho-permuted K staging, cvt_pk bf16 P-packing.
// ---------------------------------------------------------------------------
__global__ __launch_bounds__(256, 2) void attn_mfma(
    const unsigned short* __restrict__ QKV, const unsigned short* __restrict__ VT,
    const int* __restrict__ mask, unsigned short* __restrict__ O)
{
  __shared__ unsigned long long mbits[32];   // 2048-bit validity
  __shared__ unsigned short Ks[64][72];      // rho-permuted K tile [row][d]
  __shared__ unsigned short Vs[64][72];      // V^T tile [d][key]
  __shared__ unsigned short Pl[4][32][72];   // wave-private P [q][key]
  const int t = threadIdx.x;
  const int w = t>>6, lane = t&63, quad = lane>>4, l15 = lane&15;
  const int bh = blockIdx.y, b = bh>>3, hp = bh&7;
  const int q0 = blockIdx.x<<7;              // 128 queries per block
  const int qs = q0 + (w<<5);                // 32 per wave
  const int* mb = mask + b*SEQ;
  const f32x4 Z4 = {0.f,0.f,0.f,0.f};
#pragma unroll
  for (int i=0;i<8;++i){
    const unsigned long long bal = __ballot(mb[i*256 + t] != 0);
    if (lane == 0) mbits[i*4 + w] = bal;
  }

  const size_t rbase = (size_t)(b*SEQ + hp*256);   // qkv row base for this bh
  bf8 qf[2][2];
#pragma unroll
  for (int a=0;a<2;++a){
    const int q = qs + a*16 + l15;
    const unsigned short* qp =
        QKV + (rbase + (q>>3))*QKV_N + (q&7)*192 + (quad<<3);
    qf[a][0] = *reinterpret_cast<const bf8*>(qp);
    qf[a][1] = *reinterpret_cast<const bf8*>(qp + 32);
  }
  const unsigned short* Vg = VT + (size_t)bh*HDIM*SEQ;

  const int srow = t>>2, sc4 = (t&3)<<4;             // staging: key row, col
  const int krow = ((srow&3)<<4) + (srow>>2);        // rho(srow)

  f32x4 of[2][4]; float lsum[2][4];
#pragma unroll
  for (int a=0;a<2;++a)
#pragma unroll
    for (int i=0;i<4;++i){ of[a][i]=Z4; lsum[a][i]=0.f; }

  // prefetch tile 0 into registers
  uint4 gk0, gk1, gv0, gv1;
  {
    const unsigned short* kp =
        QKV + (rbase + (srow>>3))*QKV_N + (srow&7)*192 + 64 + sc4;
    gk0 = *reinterpret_cast<const uint4*>(kp);
    gk1 = *reinterpret_cast<const uint4*>(kp + 8);
    const unsigned short* vp = Vg + (size_t)srow*SEQ + sc4;
    gv0 = *reinterpret_cast<const uint4*>(vp);
    gv1 = *reinterpret_cast<const uint4*>(vp + 8);
  }
  __syncthreads();                                   // mbits visible

  for (int kt=0; kt<SEQ; kt+=64){
    *reinterpret_cast<uint4*>(&Ks[krow][sc4])   = gk0;
    *reinterpret_cast<uint4*>(&Ks[krow][sc4+8]) = gk1;
    *reinterpret_cast<uint4*>(&Vs[srow][sc4])   = gv0;
    *reinterpret_cast<uint4*>(&Vs[srow][sc4+8]) = gv1;
    __syncthreads();                                 // tiles visible

    if (kt + 64 < SEQ){                              // prefetch tile t+1
      const int kk = kt + 64 + srow;
      const unsigned short* kp =
          QKV + (rbase + (kk>>3))*QKV_N + (kk&7)*192 + 64 + sc4;
      gk0 = *reinterpret_cast<const uint4*>(kp);
      gk1 = *reinterpret_cast<const uint4*>(kp + 8);
      const unsigned short* vp = Vg + (size_t)(64+srow)*SEQ + kt + sc4;
      gv0 = *reinterpret_cast<const uint4*>(vp - 64*SEQ + 64);
      gv1 = *reinterpret_cast<const uint4*>(vp - 64*SEQ + 64 + 8);
    }

    const unsigned int msel =
        (unsigned int)(mbits[kt>>6] >> (l15<<2)) & 0xFu;

    bf8 kf[4][2];
#pragma unroll
    for (int nf=0;nf<4;++nf){
      kf[nf][0] = *reinterpret_cast<const bf8*>(&Ks[nf*16+l15][quad<<3]);
      kf[nf][1] = *reinterpret_cast<const bf8*>(&Ks[nf*16+l15][32+(quad<<3)]);
    }

#pragma unroll
    for (int a=0;a<2;++a){
      f32x4 sc[4];
#pragma unroll
      for (int nf=0;nf<4;++nf){
        f32x4 s = MFMA16(qf[a][0], kf[nf][0], Z4);
        sc[nf] = MFMA16(qf[a][1], kf[nf][1], s);
      }
      float pv[4][4];
#pragma unroll
      for (int nf=0;nf<4;++nf){
        const bool on = (msel >> nf) & 1u;
#pragma unroll
        for (int i=0;i<4;++i)
          pv[nf][i] = on ? __expf(sc[nf][i]) : 0.f;  // Q pre-scaled by 0.125
      }
#pragma unroll
      for (int i=0;i<4;++i)
        lsum[a][i] += (pv[0][i]+pv[1][i]) + (pv[2][i]+pv[3][i]);
#pragma unroll
      for (int i=0;i<4;++i){
        const unsigned int lo = pack_bf2(pv[0][i], pv[1][i]);
        const unsigned int hi = pack_bf2(pv[2][i], pv[3][i]);
        *reinterpret_cast<unsigned long long*>(&Pl[w][a*16+(quad<<2)+i][l15<<2]) =
            ((unsigned long long)hi<<32) | lo;
      }
    }

    bf8 pa[2][2];
#pragma unroll
    for (int a=0;a<2;++a){
      pa[a][0] = *reinterpret_cast<const bf8*>(&Pl[w][a*16+l15][quad<<3]);
      pa[a][1] = *reinterpret_cast<const bf8*>(&Pl[w][a*16+l15][32+(quad<<3)]);
    }
#pragma unroll
    for (int nf=0;nf<4;++nf){
      const bf8 v0 = *reinterpret_cast<const bf8*>(&Vs[nf*16+l15][quad<<3]);
      const bf8 v1 = *reinterpret_cast<const bf8*>(&Vs[nf*16+l15][32+(quad<<3)]);
#pragma unroll
      for (int a=0;a<2;++a){
        f32x4 o = MFMA16(pa[a][0], v0, of[a][nf]);
        of[a][nf] = MFMA16(pa[a][1], v1, o);
      }
    }
    __syncthreads();                                 // readers done, bufs free
  }

#pragma unroll
  for (int a=0;a<2;++a)
#pragma unroll
    for (int i=0;i<4;++i){
      float s = lsum[a][i];
      s += __shfl_xor(s,1); s += __shfl_xor(s,2);
      s += __shfl_xor(s,4); s += __shfl_xor(s,8);
      lsum[a][i] = s;
    }
  unsigned short* Op = O + (size_t)bh*SEQ*HDIM;
#pragma unroll
  for (int a=0;a<2;++a){
    const unsigned long long qw = mbits[(qs + a*16) >> 6];
#pragma unroll
    for (int i=0;i<4;++i){
      const int q = qs + a*16 + (quad<<2) + i;
      const bool qv = (qw >> (q & 63)) & 1ull;
      const float inv = (qv && lsum[a][i] > 0.f) ? 1.f/lsum[a][i] : 0.f;
#pragma unroll
      for (int nf=0;nf<4;++nf)
        Op[(size_t)q*HDIM + (nf<<4) + l15] = f2bf(of[a][nf][i]*inv);
    }
  }
}

// ---------------------------------------------------------------------------
// MFMA GEMM C (m97 structure): out = Ob @ WoutT^T, fp32 float4 stores.
// ---------------------------------------------------------------------------
__global__ __launch_bounds__(256) void gemm_out_mfma(
    const unsigned short* __restrict__ A, const unsigned short* __restrict__ Bt,
    float* __restrict__ Out)
{
  __shared__ unsigned short As[128][64];
  __shared__ unsigned short Bs[128][64];
  const int t = threadIdx.x;
  const int w = t>>6, lane = t&63, quad = lane>>4, l15 = lane&15;
  const int wr = (w>>1)<<6, wc = (w&1)<<6;
  const int m0 = blockIdx.y<<7, n0 = blockIdx.x<<7;
  const int row = t>>3, seg = t&7;
  const unsigned short* Agp = A  + (size_t)(m0+row)*DMODEL + seg*8;
  const unsigned short* Bgp = Bt + (size_t)(n0+row)*DMODEL + seg*8;
  f32x4 acc[4][4];
#pragma unroll
  for (int i=0;i<4;++i)
#pragma unroll
    for (int j=0;j<4;++j) acc[i][j] = (f32x4){0.f,0.f,0.f,0.f};

  for (int k0=0;k0<DMODEL;k0+=64){
    __syncthreads();
#pragma unroll
    for (int p=0;p<4;++p){
      gload_lds16(Agp + (size_t)p*32*DMODEL + k0, &As[(w<<3)+(p<<5)][0]);
      gload_lds16(Bgp + (size_t)p*32*DMODEL + k0, &Bs[(w<<3)+(p<<5)][0]);
    }
    __syncthreads();
#pragma unroll
    for (int ks=0;ks<2;++ks){
      bf8 af[4], bfr[4];
#pragma unroll
      for (int mi=0;mi<4;++mi)
        af[mi]  = *reinterpret_cast<const bf8*>(&As[wr+mi*16+l15][ks*32+quad*8]);
#pragma unroll
      for (int nj=0;nj<4;++nj)
        bfr[nj] = *reinterpret_cast<const bf8*>(&Bs[wc+(l15<<2)+nj][ks*32+quad*8]);
#pragma unroll
      for (int mi=0;mi<4;++mi)
#pragma unroll
        for (int nj=0;nj<4;++nj) acc[mi][nj] = MFMA16(af[mi], bfr[nj], acc[mi][nj]);
    }
  }
  const int cbase = n0 + wc + (l15<<2);
#pragma unroll
  for (int mi=0;mi<4;++mi)
#pragma unroll
    for (int i=0;i<4;++i){
      const int m = m0 + wr + mi*16 + quad*4 + i;
      const float4 o = make_float4(acc[mi][0][i], acc[mi][1][i],
                                   acc[mi][2][i], acc[mi][3][i]);
      *reinterpret_cast<float4*>(Out + (size_t)m*DMODEL + cbase) = o;
    }
}

// ---------------------------------------------------------------------------
extern "C" void kernel_launch(void* const* d_in, const int* in_sizes, int n_in,
                              void* d_out, int out_size, void* d_ws, size_t ws_size,
                              hipStream_t stream) {
  (void)in_sizes; (void)n_in; (void)out_size; (void)ws_size;
  const float* x     = (const float*)d_in[0];
  const int*   pmask = (const int*)d_in[2];
  const float* Wqkv  = (const float*)d_in[3];
  const float* Wout  = (const float*)d_in[4];
  float* out = (float*)d_out;

  const size_t per = (size_t)BATCH*NHEADS*SEQ*HDIM;     // 4,194,304
  unsigned short* Xh    = (unsigned short*)d_ws;
  unsigned short* WqkvT = Xh    + (size_t)8192*512;
  unsigned short* WoutT = WqkvT + (size_t)1536*512;
  unsigned short* QKVb  = WoutT + (size_t)512*512;
  unsigned short* VbT   = QKVb  + (size_t)8192*QKV_N;
  unsigned short* Ob    = VbT + per;                    // ~52 MB total

  prep<<<2304, 256, 0, stream>>>(x, Wqkv, Wout, Xh, WqkvT, WoutT);
  gemm_qkv_mfma<<<dim3(QKV_N/128, 8192/128), 256, 0, stream>>>(Xh, WqkvT, QKVb);
  v_transpose<<<dim3(SEQ/64, BATCH*NHEADS), 256, 0, stream>>>(QKVb, VbT);
  attn_mfma<<<dim3(SEQ/128, BATCH*NHEADS), 256, 0, stream>>>(QKVb, VbT, pmask, Ob);
  gemm_out_mfma<<<dim3(DMODEL/128, 8192/128), 256, 0, stream>>>(Ob, WoutT, out);
}